// Round 9
// baseline (630.599 us; speedup 1.0000x reference)
//
#include <hip/hip_runtime.h>
#include <hip/hip_bf16.h>
#include <hip/hip_fp16.h>

// GCN 3-layer: x(N,12) -> 64 -> 128 -> 96, symmetric normalization + self loops.
// N=100000, E=1600000.
//
// R2: CSR + pull-gather (7028 -> 1364 us).           R3: 4x4-tile transform (-> 693).
// R4: aggregate at min-width 12/64/96, prescale (-> 550).
// R5/R6/R8: bucketed CSR build, nt stores, degree sort (-> 444).
// R9: fp16 feature rows for gathers (-> 382).
// R10: v_dot2_f32_f16 transforms + packed edge binning (-> 352).
// R11: layers 2+3 fused into ONE MFMA kernel; LPT gather order (-> 328).
// R12: unroll-8 index-prefetched gathers; fp16 layer-1 gather (neutral).
// R13/R14: csr_fill@1024, packed hdr (-> 324).
// R15: fused grid x2, hdr-in-dperm, gather_x+t1 fusion (-> 329, flat).
// R16: __launch_bounds__(256,2) on fused killed a 150MB accumulator spill (-> 289).
// R17: per-lane register gather fused into MFMA: REGRESSED (scratch + lost MLP).
// R18: block-cooperative g64+MFMA fusion (proven gather loop -> LDS -> proven
//      MFMA path, overlaid buffers) (-> 276).
// R19: XCD-SLICED final gather. g96's FETCH was 183MB for a 19.2MB table:
//      random access from all 8 XCDs -> 4MB private L2 hit rate ~44%, bound by
//      the L2-miss path. Split 96 features into 8 slices of 12 (2.4MB/slice);
//      slice = blockIdx&7 pins each slice to one XCD (dispatch round-robin
//      heuristic) -> slice becomes L2-resident, gathers become L2 hits.
//      csr_src/hdr streamed 8x (sequential) in exchange. Identical edge order
//      per feature -> bit-identical output.

static inline int cdiv(int a, int b) { return (a + b - 1) / b; }
constexpr int BLOCK = 256;
constexpr int BSHIFT = 9;                  // 512 nodes per bucket
constexpr int BNODES = 1 << BSHIFT;

typedef float nfloat4 __attribute__((ext_vector_type(4)));
typedef _Float16 f16x8 __attribute__((ext_vector_type(8)));
typedef float f32x16 __attribute__((ext_vector_type(16)));

// ---------------- small utils ----------------

__device__ __forceinline__ void nt_store_raw16(void* p, float4 v) {
    nfloat4 nv;
    nv.x = v.x; nv.y = v.y; nv.z = v.z; nv.w = v.w;
    __builtin_nontemporal_store(nv, (nfloat4*)p);
}

struct h4 { __half2 a, b; };  // 8 bytes = 4 fp16
__device__ __forceinline__ void store_h4(__half* p, float4 v) {
    h4 r;
    r.a = __floats2half2_rn(v.x, v.y);
    r.b = __floats2half2_rn(v.z, v.w);
    *(h4*)p = r;
}

// unpack 8 fp16 (one float4 raw load) and add into acc[0..7]
__device__ __forceinline__ void h8_add(float* acc, float4 raw) {
    union { float4 f; __half2 h[4]; } u;
    u.f = raw;
#pragma unroll
    for (int j = 0; j < 4; ++j) {
        float2 p = __half22float2(u.h[j]);
        acc[2 * j] += p.x;
        acc[2 * j + 1] += p.y;
    }
}

// unpack 4 fp16 (one float2 raw load) and add into acc[0..3]
__device__ __forceinline__ void h4_add(float* acc, float2 raw) {
    union { float2 f; __half2 h[2]; } u;
    u.f = raw;
    float2 p0 = __half22float2(u.h[0]);
    float2 p1 = __half22float2(u.h[1]);
    acc[0] += p0.x; acc[1] += p0.y; acc[2] += p1.x; acc[3] += p1.y;
}

__device__ __forceinline__ void h4_set(float* acc, float2 raw) {
    union { float2 f; __half2 h[2]; } u;
    u.f = raw;
    float2 p0 = __half22float2(u.h[0]);
    float2 p1 = __half22float2(u.h[1]);
    acc[0] = p0.x; acc[1] = p0.y; acc[2] = p1.x; acc[3] = p1.y;
}

// ---------------- CSR build (fully bucketed) ----------------

template <int CHUNK>
__global__ void bucket_count_kernel(const int* __restrict__ dst, int E,
                                    int* __restrict__ bcnt, int NB) {
    __shared__ int cnt[256];
    for (int i = threadIdx.x; i < NB; i += blockDim.x) cnt[i] = 0;
    __syncthreads();
    const int e0 = blockIdx.x * CHUNK;
    const int e1 = min(e0 + CHUNK, E);
    for (int e = e0 + threadIdx.x; e < e1; e += blockDim.x)
        atomicAdd(&cnt[dst[e] >> BSHIFT], 1);
    __syncthreads();
    for (int i = threadIdx.x; i < NB; i += blockDim.x)
        if (cnt[i]) atomicAdd(&bcnt[i], cnt[i]);
}

__global__ void bucket_scan_kernel(const int* __restrict__ bcnt, int* __restrict__ gbase,
                                   int* __restrict__ gcur, int NB) {
    __shared__ int tmp[256];
    int t = threadIdx.x;
    int v = (t < NB) ? bcnt[t] : 0;
    tmp[t] = v;
    __syncthreads();
    for (int off = 1; off < 256; off <<= 1) {
        int add = (t >= off) ? tmp[t - off] : 0;
        __syncthreads();
        tmp[t] += add;
        __syncthreads();
    }
    if (t < NB) { int ex = tmp[t] - v; gbase[t] = ex; gcur[t] = ex; }
}

// Phase A: bin edges by dst bucket; entry packed as s | (dst_local << 17)
template <int CHUNK>
__global__ void bin_edges_kernel(const int* __restrict__ ei, int E,
                                 int* __restrict__ gcur, unsigned* __restrict__ binned,
                                 int NB) {
    __shared__ int cnt[256], base[256], rk[256];
    for (int i = threadIdx.x; i < NB; i += blockDim.x) { cnt[i] = 0; rk[i] = 0; }
    __syncthreads();
    const int e0 = blockIdx.x * CHUNK;
    const int e1 = min(e0 + CHUNK, E);
    for (int e = e0 + threadIdx.x; e < e1; e += blockDim.x)
        atomicAdd(&cnt[ei[E + e] >> BSHIFT], 1);
    __syncthreads();
    for (int i = threadIdx.x; i < NB; i += blockDim.x)
        base[i] = atomicAdd(&gcur[i], cnt[i]);
    __syncthreads();
    for (int e = e0 + threadIdx.x; e < e1; e += blockDim.x) {
        int s = ei[e], d = ei[E + e];
        int b = d >> BSHIFT;
        int r = atomicAdd(&rk[b], 1);
        binned[base[b] + r] = (unsigned)s | ((unsigned)(d & (BNODES - 1)) << 17);
    }
}

// Phase B: one block per bucket, 1024 threads (16 waves). LDS degree hist +
// pair-scan on first 256 threads -> deg/dinv/row_ptr; scatter csr_src in
// L2-local window; 64-bin degree hist folded in.
__global__ void csr_fill_kernel(const int* __restrict__ gbase, const int* __restrict__ bcnt,
                                const unsigned* __restrict__ binned,
                                int* __restrict__ deg, float* __restrict__ dinv,
                                int* __restrict__ row_ptr, int* __restrict__ csr_src,
                                int* __restrict__ dh, int N) {
    __shared__ int c[BNODES];    // counts, then cursors
    __shared__ int ps[256];      // pair sums for scan
    __shared__ int dhloc[64];
    const int t = threadIdx.x;   // 0..1023
    const int b = blockIdx.x;
    const int node0 = b << BSHIFT;
    if (t < BNODES) c[t] = 0;
    if (t < 64) dhloc[t] = 0;
    __syncthreads();
    const int base = gbase[b];
    const int end = base + bcnt[b];
    for (int e = base + t; e < end; e += 1024)
        atomicAdd(&c[binned[e] >> 17], 1);
    __syncthreads();
    int s0 = 0, s1 = 0;
    if (t < 256) {
        s0 = c[2 * t]; s1 = c[2 * t + 1];
        ps[t] = s0 + s1;
    }
    __syncthreads();
    for (int off = 1; off < 256; off <<= 1) {
        int add = (t >= off && t < 256) ? ps[t - off] : 0;
        __syncthreads();
        if (t < 256) ps[t] += add;
        __syncthreads();
    }
    if (t < 256) {
        const int ex = ps[t] - (s0 + s1);
        const int p0 = base + ex;
        const int p1 = p0 + s0;
        const int n0 = node0 + 2 * t;
        if (n0 < N) {
            row_ptr[n0] = p0; deg[n0] = s0; dinv[n0] = rsqrtf((float)s0 + 1.0f);
            atomicAdd(&dhloc[min(s0, 63)], 1);
            if (n0 + 1 < N) {
                row_ptr[n0 + 1] = p1; deg[n0 + 1] = s1; dinv[n0 + 1] = rsqrtf((float)s1 + 1.0f);
                atomicAdd(&dhloc[min(s1, 63)], 1);
            }
        }
        c[2 * t] = p0; c[2 * t + 1] = p1;
    }
    __syncthreads();
    if (t < 64 && dhloc[t]) atomicAdd(&dh[t], dhloc[t]);
    for (int e = base + t; e < end; e += 1024) {
        unsigned sd = binned[e];
        int pos = atomicAdd(&c[sd >> 17], 1);
        csr_src[pos] = (int)(sd & 0x1FFFFu);
    }
}

// ---------------- degree counting sort (64 bins) -> packed headers ----------------

__global__ void dscan_kernel(int* __restrict__ dh) {
    __shared__ int tmp[64];
    int t = threadIdx.x;
    int v = dh[t];
    tmp[t] = v;
    __syncthreads();
    for (int off = 1; off < 64; off <<= 1) {
        int add = (t >= off) ? tmp[t - off] : 0;
        __syncthreads();
        tmp[t] += add;
        __syncthreads();
    }
    dh[t] = tmp[t] - v;
}

// counting-sort scatter that writes packed headers DIRECTLY. hdr[N-1-slot] =
// {row_ptr, deg, node, dinv_bits}: slot 0 = highest degree (LPT).
__global__ void dperm_kernel(const int* __restrict__ deg, const int* __restrict__ row_ptr,
                             const float* __restrict__ dinv, int* __restrict__ dh,
                             int4* __restrict__ hdr, int N) {
    __shared__ int cnt[64], base[64], rk[64];
    const int t = threadIdx.x;
    if (t < 64) { cnt[t] = 0; rk[t] = 0; }
    __syncthreads();
    const int i = blockIdx.x * blockDim.x + t;
    const int d = (i < N) ? deg[i] : 0;
    const int myb = (i < N) ? min(d, 63) : -1;
    if (myb >= 0) atomicAdd(&cnt[myb], 1);
    __syncthreads();
    if (t < 64) base[t] = cnt[t] ? atomicAdd(&dh[t], cnt[t]) : 0;
    __syncthreads();
    if (myb >= 0) {
        int r = atomicAdd(&rk[myb], 1);
        int slot = base[myb] + r;
        int4 h;
        h.x = row_ptr[i];
        h.y = d;
        h.z = i;
        h.w = __float_as_int(dinv[i]);
        hdr[N - 1 - slot] = h;
    }
}

// ---------------- prescale: x (N,12) f32 -> xs (N,16) f16, scaled by dinv ----

__global__ void prescale_h_kernel(const float* __restrict__ x, const float* __restrict__ dinv,
                                  __half* __restrict__ xs, int N) {
    int i = blockIdx.x * blockDim.x + threadIdx.x;
    if (i >= N) return;
    float di = dinv[i];
    const float4* xr = (const float4*)(x + (size_t)i * 12);
    float4 a = xr[0], b = xr[1], c = xr[2];
    union { float4 f; __half2 h[4]; } u0, u1;
    u0.h[0] = __floats2half2_rn(a.x * di, a.y * di);
    u0.h[1] = __floats2half2_rn(a.z * di, a.w * di);
    u0.h[2] = __floats2half2_rn(b.x * di, b.y * di);
    u0.h[3] = __floats2half2_rn(b.z * di, b.w * di);
    u1.h[0] = __floats2half2_rn(c.x * di, c.y * di);
    u1.h[1] = __floats2half2_rn(c.z * di, c.w * di);
    u1.h[2] = __floats2half2_rn(0.f, 0.f);
    u1.h[3] = __floats2half2_rn(0.f, 0.f);
    float4* op = (float4*)(xs + (size_t)i * 16);
    op[0] = u0.f;
    op[1] = u1.f;
}

// ---------------- fused gather_x + transform-1 ----------------

// Phase 1: aggregate xs (fp16 [N][16], prescaled) at F=16h, 2 threads/node,
// results (scaled by dinv) into LDS xrow[128][12].  Phase 2: 12->64 transform
// from LDS-resident W1 (+b1, relu, *dinv) -> h1h fp16 rows.
__global__ void gather_x_t1_kernel(const int4* __restrict__ hdr,
                                   const int* __restrict__ csr_src,
                                   const __half* __restrict__ xs,
                                   const float* __restrict__ W1,
                                   const float* __restrict__ b1,
                                   __half* __restrict__ h1h, int N) {
    __shared__ float W1s[12 * 64];    // 3 KB
    __shared__ float xrow[128][12];   // 6 KB
    const int tid = threadIdx.x;
    for (int u = tid; u < 12 * 64 / 4; u += 256)
        ((float4*)W1s)[u] = ((const float4*)W1)[u];

    const int t = blockIdx.x * 256 + tid;
    const bool valid = (t < N * 2);
    const int slot = t >> 1;
    const int c = t & 1;
    const int nl = tid >> 1;
    int4 H = valid ? hdr[slot] : make_int4(0, 0, 0, 0);
    const int* __restrict__ sp = csr_src + H.x;
    const int n = valid ? H.y : 0;
    const int i = H.z;
    const float di = __int_as_float(H.w);
    const int f0 = c * 8;

    float acc[8];
    {
        union { float4 f; __half2 h[4]; } u;
        u.f = *(const float4*)(xs + (size_t)i * 16 + f0);  // self loop
#pragma unroll
        for (int j = 0; j < 4; ++j) {
            float2 p = __half22float2(u.h[j]);
            acc[2 * j] = p.x; acc[2 * j + 1] = p.y;
        }
    }

    int k = 0;
    if (n >= 8) {
        int s[8];
#pragma unroll
        for (int j = 0; j < 8; ++j) s[j] = sp[j];
        for (; k + 16 <= n; k += 8) {
            int ns[8];
#pragma unroll
            for (int j = 0; j < 8; ++j) ns[j] = sp[k + 8 + j];
            float4 v[8];
#pragma unroll
            for (int j = 0; j < 8; ++j) v[j] = *(const float4*)(xs + (size_t)s[j] * 16 + f0);
#pragma unroll
            for (int j = 0; j < 8; ++j) h8_add(acc, v[j]);
#pragma unroll
            for (int j = 0; j < 8; ++j) s[j] = ns[j];
        }
        float4 v[8];
#pragma unroll
        for (int j = 0; j < 8; ++j) v[j] = *(const float4*)(xs + (size_t)s[j] * 16 + f0);
#pragma unroll
        for (int j = 0; j < 8; ++j) h8_add(acc, v[j]);
        k += 8;
    }
    for (; k + 4 <= n; k += 4) {
        int s0 = sp[k + 0], s1 = sp[k + 1], s2 = sp[k + 2], s3 = sp[k + 3];
        float4 v0 = *(const float4*)(xs + (size_t)s0 * 16 + f0);
        float4 v1 = *(const float4*)(xs + (size_t)s1 * 16 + f0);
        float4 v2 = *(const float4*)(xs + (size_t)s2 * 16 + f0);
        float4 v3 = *(const float4*)(xs + (size_t)s3 * 16 + f0);
        h8_add(acc, v0); h8_add(acc, v1); h8_add(acc, v2); h8_add(acc, v3);
    }
    for (; k < n; ++k) {
        float4 v = *(const float4*)(xs + (size_t)sp[k] * 16 + f0);
        h8_add(acc, v);
    }

    if (valid) {
        if (c == 0) {
#pragma unroll
            for (int j = 0; j < 8; ++j) xrow[nl][j] = acc[j] * di;
        } else {
#pragma unroll
            for (int j = 0; j < 4; ++j) xrow[nl][8 + j] = acc[j] * di;  // f 8..11
        }
    }
    __syncthreads();
    if (!valid) return;

    float xr[12];
#pragma unroll
    for (int j = 0; j < 12; ++j) xr[j] = xrow[nl][j];

    __half* op = h1h + (size_t)i * 64 + c * 32;
#pragma unroll
    for (int g = 0; g < 8; ++g) {
        const int c0 = c * 32 + g * 4;
        float4 r = *(const float4*)(b1 + c0);
#pragma unroll
        for (int kk = 0; kk < 12; ++kk) {
            const float4 w = *(const float4*)(W1s + kk * 64 + c0);
            r.x = fmaf(xr[kk], w.x, r.x);
            r.y = fmaf(xr[kk], w.y, r.y);
            r.z = fmaf(xr[kk], w.z, r.z);
            r.w = fmaf(xr[kk], w.w, r.w);
        }
        r.x = fmaxf(r.x, 0.f) * di; r.y = fmaxf(r.y, 0.f) * di;
        r.z = fmaxf(r.z, 0.f) * di; r.w = fmaxf(r.w, 0.f) * di;
        store_h4(op + g * 4, r);
    }
}

// ---------------- fused gather64 (block-coop) + MFMA layers 2+3 ----------------

// prep: W2 (64x128 f32, k-major) -> W2T (128x64 f16, n-major);
//       W3 (128x96 f32)          -> W3T (96x128 f16, n-major).
__global__ void prep_w_kernel(const float* __restrict__ W2, const float* __restrict__ W3,
                              __half* __restrict__ W2T, __half* __restrict__ W3T) {
    int i = blockIdx.x * 256 + threadIdx.x;
    if (i < 64 * 128) {
        int k = i >> 7, n = i & 127;
        W2T[n * 64 + k] = __float2half(W2[i]);
    } else {
        int j = i - 64 * 128;
        if (j < 128 * 96) {
            int k = j / 96, n = j - k * 96;
            W3T[n * 128 + k] = __float2half(W3[j]);
        }
    }
}

// Block handles 4 tiles (128 rows), 1 per wave.
// Phase 1 (block-wide): PROVEN gather64 loop (8 threads/node, 16B/edge, fp32
//   accum, unroll-8 prefetch) -> agg rows (fp16, *dinv) into LDS buf[p].
// Phase 2 (per wave, after 1 barrier): PROVEN t2/t3 MFMA path; A-frags read
//   from buf[wid]; h2 OVERLAYS the same region (a2 fully register-buffered
//   before overwrite; DS ops in-order per wave -> safe, no extra barrier).
// Frag layouts (gfx950, guide-verified):
//   A: lane holds A[row=l&31][k = kb*16 + (l>>5)*8 + j], j=0..7
//   B: lane holds B[k = kb*16 + (l>>5)*8 + j][col=l&31]  (n-major W^T rows)
//   C/D: elem r -> row = (r&3) + 8*(r>>2) + 4*(l>>5), col = l&31
// LB(256,2): 256-VGPR cap (spill-proof, as R16); LDS 34.8KB -> 4 blocks/CU.
__global__ void __launch_bounds__(256, 2)
fused_g64_t2t3_kernel(const __half* __restrict__ h1h,   // [N][64] f16 (pre-scaled rows)
                      const int* __restrict__ row_ptr, const int* __restrict__ deg,
                      const int* __restrict__ csr_src, const float* __restrict__ dinv,
                      const __half* __restrict__ W2T,   // [128][64] f16
                      const float* __restrict__ b2,     // [128]
                      const __half* __restrict__ W3T,   // [96][128] f16
                      __half* __restrict__ out,         // [N][96] f16
                      int N) {
    constexpr int LDH = 136;  // halves; 272B rows: 16B-aligned
    __shared__ _Float16 buf[4][32 * LDH];  // agg tiles, overlaid by h2 in phase 2
    const int tid = threadIdx.x;
    const int lane = tid & 63;
    const int wid = tid >> 6;
    const int l31 = lane & 31;
    const int lh = lane >> 5;  // 0/1
    const int NT = N >> 5;     // N % 32 == 0
    const int t0 = blockIdx.x * 4;

    // ---- phase 1: block-cooperative gather64 into LDS ----
    {
        const int nr = tid >> 3;        // node-row within tile (0..31)
        const int f0 = (tid & 7) * 8;   // feature start (halves)
#pragma unroll 1
        for (int p = 0; p < 4; ++p) {
            const int t = t0 + p;       // block-uniform
            if (t >= NT) break;
            const int i = (t << 5) + nr;
            const int* __restrict__ sp = csr_src + row_ptr[i];
            const int n = deg[i];
            const float di = dinv[i];

            float acc[8];
            {
                union { float4 f; __half2 h[4]; } u;
                u.f = *(const float4*)(h1h + (size_t)i * 64 + f0);  // self loop
#pragma unroll
                for (int j = 0; j < 4; ++j) {
                    float2 pp = __half22float2(u.h[j]);
                    acc[2 * j] = pp.x; acc[2 * j + 1] = pp.y;
                }
            }

            int k = 0;
            if (n >= 8) {
                int s[8];
#pragma unroll
                for (int j = 0; j < 8; ++j) s[j] = sp[j];
                for (; k + 16 <= n; k += 8) {
                    int ns[8];
#pragma unroll
                    for (int j = 0; j < 8; ++j) ns[j] = sp[k + 8 + j];
                    float4 v[8];
#pragma unroll
                    for (int j = 0; j < 8; ++j) v[j] = *(const float4*)(h1h + (size_t)s[j] * 64 + f0);
#pragma unroll
                    for (int j = 0; j < 8; ++j) h8_add(acc, v[j]);
#pragma unroll
                    for (int j = 0; j < 8; ++j) s[j] = ns[j];
                }
                float4 v[8];
#pragma unroll
                for (int j = 0; j < 8; ++j) v[j] = *(const float4*)(h1h + (size_t)s[j] * 64 + f0);
#pragma unroll
                for (int j = 0; j < 8; ++j) h8_add(acc, v[j]);
                k += 8;
            }
            for (; k + 4 <= n; k += 4) {
                int s0 = sp[k + 0], s1 = sp[k + 1], s2 = sp[k + 2], s3 = sp[k + 3];
                float4 v0 = *(const float4*)(h1h + (size_t)s0 * 64 + f0);
                float4 v1 = *(const float4*)(h1h + (size_t)s1 * 64 + f0);
                float4 v2 = *(const float4*)(h1h + (size_t)s2 * 64 + f0);
                float4 v3 = *(const float4*)(h1h + (size_t)s3 * 64 + f0);
                h8_add(acc, v0); h8_add(acc, v1); h8_add(acc, v2); h8_add(acc, v3);
            }
            for (; k < n; ++k) {
                float4 v = *(const float4*)(h1h + (size_t)sp[k] * 64 + f0);
                h8_add(acc, v);
            }

            union { float4 f; __half2 h[4]; } o;
            o.h[0] = __floats2half2_rn(acc[0] * di, acc[1] * di);
            o.h[1] = __floats2half2_rn(acc[2] * di, acc[3] * di);
            o.h[2] = __floats2half2_rn(acc[4] * di, acc[5] * di);
            o.h[3] = __floats2half2_rn(acc[6] * di, acc[7] * di);
            *(float4*)(&buf[p][nr * LDH + f0]) = o.f;
        }
    }
    __syncthreads();

    // ---- phase 2: per-wave t2/t3 MFMA on tile t0+wid ----
    const int t = t0 + wid;
    if (t >= NT) return;
    const int r0 = t << 5;
    _Float16* hs = buf[wid];

    float b2v[4];
#pragma unroll
    for (int nt = 0; nt < 4; ++nt) b2v[nt] = b2[nt * 32 + l31];

    // A-frags from LDS (agg rows), fully register-buffered before overwrite
    f16x8 a2[4];
#pragma unroll
    for (int kb = 0; kb < 4; ++kb)
        a2[kb] = *(const f16x8*)(hs + l31 * LDH + kb * 16 + lh * 8);

    // ---- t2 ----
#pragma unroll
    for (int nt = 0; nt < 4; ++nt) {
        f32x16 c = {0.f, 0.f, 0.f, 0.f, 0.f, 0.f, 0.f, 0.f,
                    0.f, 0.f, 0.f, 0.f, 0.f, 0.f, 0.f, 0.f};
#pragma unroll
        for (int kb = 0; kb < 4; ++kb) {
            f16x8 b = *(const f16x8*)(W2T + (size_t)(nt * 32 + l31) * 64 + kb * 16 + lh * 8);
            c = __builtin_amdgcn_mfma_f32_32x32x16_f16(a2[kb], b, c, 0, 0, 0);
        }
#pragma unroll
        for (int r = 0; r < 16; ++r) {
            int row = (r & 3) + 8 * (r >> 2) + 4 * lh;
            float v = fmaxf(c[r] + b2v[nt], 0.f);
            hs[row * LDH + nt * 32 + l31] = (_Float16)v;
        }
    }

    // ---- t3 ----
    f16x8 a3[8];
#pragma unroll
    for (int kb = 0; kb < 8; ++kb)
        a3[kb] = *(const f16x8*)(hs + l31 * LDH + kb * 16 + lh * 8);
    float4 dv[4];
#pragma unroll
    for (int rg = 0; rg < 4; ++rg)
        dv[rg] = *(const float4*)(dinv + r0 + rg * 8 + lh * 4);
#pragma unroll
    for (int nt = 0; nt < 3; ++nt) {
        f32x16 c = {0.f, 0.f, 0.f, 0.f, 0.f, 0.f, 0.f, 0.f,
                    0.f, 0.f, 0.f, 0.f, 0.f, 0.f, 0.f, 0.f};
#pragma unroll
        for (int kb = 0; kb < 8; ++kb) {
            f16x8 b = *(const f16x8*)(W3T + (size_t)(nt * 32 + l31) * 128 + kb * 16 + lh * 8);
            c = __builtin_amdgcn_mfma_f32_32x32x16_f16(a3[kb], b, c, 0, 0, 0);
        }
#pragma unroll
        for (int r = 0; r < 16; ++r) {
            int row = (r & 3) + 8 * (r >> 2) + 4 * lh;
            float dvv = ((const float*)&dv[r >> 2])[r & 3];
            hs[row * LDH + nt * 32 + l31] = (_Float16)(c[r] * dvv);
        }
    }

    // ---- coalesced out-tile store: 32 rows x 192B = 6KB contiguous ----
#pragma unroll
    for (int it = 0; it < 6; ++it) {
        int id = lane + it * 64;       // 384 16B-chunks
        int row = id / 12, ch = id - row * 12;
        float4 v = *(const float4*)(hs + row * LDH + ch * 8);
        *(float4*)((char*)(out + (size_t)r0 * 96) + (size_t)id * 16) = v;
    }
}

// ---------------- XCD-sliced final gather (F=96, 8 slices x 12 features) ----------------

// slice = blockIdx&7 -> pinned to one XCD (dispatch round-robin heuristic), so
// each XCD's 4MB L2 holds only its 2.4MB slice of hw3h -> edge gathers hit L2.
// One thread per node per slice: 12 features, 3x float2 loads/edge (24B,
// 8B-aligned), fp32 accum in identical edge order -> bit-identical results.
__global__ void __launch_bounds__(256)
gather96_slice_kernel(const int4* __restrict__ hdr, const int* __restrict__ csr_src,
                      const __half* __restrict__ hws, const float* __restrict__ b,
                      float* __restrict__ out, int N) {
    const int bid = blockIdx.x;
    const int slice = bid & 7;
    const int slot = (bid >> 3) * 256 + threadIdx.x;
    if (slot >= N) return;
    const int4 H = hdr[slot];
    const int* __restrict__ sp = csr_src + H.x;
    const int n = H.y;
    const int i = H.z;
    const float di = __int_as_float(H.w);
    const size_t foff = (size_t)slice * 24;          // byte offset within 192B row
    const char* __restrict__ tb = (const char*)hws;

    float acc[12];
    {
        const char* rp = tb + (size_t)i * 192 + foff;  // self loop
        h4_set(acc + 0, *(const float2*)(rp));
        h4_set(acc + 4, *(const float2*)(rp + 8));
        h4_set(acc + 8, *(const float2*)(rp + 16));
    }

    int k = 0;
    if (n >= 8) {
        int s[8];
#pragma unroll
        for (int j = 0; j < 8; ++j) s[j] = sp[j];
        for (; k + 16 <= n; k += 8) {
            int ns[8];
#pragma unroll
            for (int j = 0; j < 8; ++j) ns[j] = sp[k + 8 + j];
#pragma unroll
            for (int j = 0; j < 8; ++j) {
                const char* p = tb + (size_t)s[j] * 192 + foff;
                h4_add(acc + 0, *(const float2*)(p));
                h4_add(acc + 4, *(const float2*)(p + 8));
                h4_add(acc + 8, *(const float2*)(p + 16));
            }
#pragma unroll
            for (int j = 0; j < 8; ++j) s[j] = ns[j];
        }
#pragma unroll
        for (int j = 0; j < 8; ++j) {
            const char* p = tb + (size_t)s[j] * 192 + foff;
            h4_add(acc + 0, *(const float2*)(p));
            h4_add(acc + 4, *(const float2*)(p + 8));
            h4_add(acc + 8, *(const float2*)(p + 16));
        }
        k += 8;
    }
    for (; k < n; ++k) {
        const char* p = tb + (size_t)sp[k] * 192 + foff;
        h4_add(acc + 0, *(const float2*)(p));
        h4_add(acc + 4, *(const float2*)(p + 8));
        h4_add(acc + 8, *(const float2*)(p + 16));
    }

    const float4 bb0 = *(const float4*)(b + slice * 12);
    const float4 bb1 = *(const float4*)(b + slice * 12 + 4);
    const float4 bb2 = *(const float4*)(b + slice * 12 + 8);
    float4 r0, r1, r2;
    r0.x = fmaf(acc[0], di, bb0.x); r0.y = fmaf(acc[1], di, bb0.y);
    r0.z = fmaf(acc[2], di, bb0.z); r0.w = fmaf(acc[3], di, bb0.w);
    r1.x = fmaf(acc[4], di, bb1.x); r1.y = fmaf(acc[5], di, bb1.y);
    r1.z = fmaf(acc[6], di, bb1.z); r1.w = fmaf(acc[7], di, bb1.w);
    r2.x = fmaf(acc[8], di, bb2.x); r2.y = fmaf(acc[9], di, bb2.y);
    r2.z = fmaf(acc[10], di, bb2.z); r2.w = fmaf(acc[11], di, bb2.w);
    float* op = out + (size_t)i * 96 + slice * 12;
    nt_store_raw16(op, r0);
    nt_store_raw16(op + 4, r1);
    nt_store_raw16(op + 8, r2);
}

// ---------------- launch ----------------

extern "C" void kernel_launch(void* const* d_in, const int* in_sizes, int n_in,
                              void* d_out, int out_size, void* d_ws, size_t ws_size,
                              hipStream_t stream) {
    const float* x  = (const float*)d_in[0];
    const int*   ei = (const int*)d_in[1];  // (2,E): row0=src, row1=dst
    const float* W1 = (const float*)d_in[2];
    const float* b1 = (const float*)d_in[3];
    const float* W2 = (const float*)d_in[4];
    const float* b2 = (const float*)d_in[5];
    const float* W3 = (const float*)d_in[6];
    const float* b3 = (const float*)d_in[7];
    float* out = (float*)d_out;

    const int N = in_sizes[0] / 12;
    const int E = in_sizes[1] / 2;
    const int NB = cdiv(N, BNODES);  // 196 dst buckets (<=256)

    // workspace layout
    char* ws = (char*)d_ws;
    int*   deg     = (int*)ws;    ws += (size_t)N * sizeof(int);
    int*   row_ptr = (int*)ws;    ws += (size_t)N * sizeof(int);
    int*   bcnt    = (int*)ws;    ws += 256 * sizeof(int);
    int*   dh      = (int*)ws;    ws += 64 * sizeof(int);
    int*   gbase   = (int*)ws;    ws += 256 * sizeof(int);
    int*   gcur    = (int*)ws;    ws += 256 * sizeof(int);
    float* dinv    = (float*)ws;  ws += (size_t)N * sizeof(float);
    int4*  hdr     = (int4*)ws;   ws += (size_t)N * sizeof(int4);
    __half* W2Th   = (__half*)ws; ws += 128 * 64 * sizeof(__half);
    __half* W3Th   = (__half*)ws; ws += 96 * 128 * sizeof(__half);
    int*   csr_src = (int*)ws;    ws += (size_t)E * sizeof(int);
    float* bufA    = (float*)ws;  ws += (size_t)N * 128 * sizeof(float);  // xs / hw3h
    float* bufB    = (float*)ws;                                          // binned / h1h
    unsigned* binned = (unsigned*)bufB;  // aliased: consumed before bufB reused

    // ---- CSR build (fully bucketed) + weight prep ----
    hipMemsetAsync(bcnt, 0, (256 + 64) * sizeof(int), stream);  // bcnt + dh (contiguous)
    prep_w_kernel<<<80, 256, 0, stream>>>(W2, W3, W2Th, W3Th);
    bucket_count_kernel<8192><<<cdiv(E, 8192), BLOCK, 0, stream>>>(ei + E, E, bcnt, NB);
    bucket_scan_kernel<<<1, 256, 0, stream>>>(bcnt, gbase, gcur, NB);
    bin_edges_kernel<8192><<<cdiv(E, 8192), BLOCK, 0, stream>>>(ei, E, gcur, binned, NB);
    csr_fill_kernel<<<NB, 1024, 0, stream>>>(gbase, bcnt, binned, deg, dinv, row_ptr,
                                             csr_src, dh, N);

    // ---- degree counting sort -> packed headers ----
    dscan_kernel<<<1, 64, 0, stream>>>(dh);
    dperm_kernel<<<cdiv(N, BLOCK), BLOCK, 0, stream>>>(deg, row_ptr, dinv, dh, hdr, N);

    // ---- layer 1: prescale->fp16, fused aggregate@F=16h + 12->64 transform ----
    prescale_h_kernel<<<cdiv(N, BLOCK), BLOCK, 0, stream>>>(x, dinv, (__half*)bufA, N);
    gather_x_t1_kernel<<<cdiv(N * 2, BLOCK), BLOCK, 0, stream>>>(
        hdr, csr_src, (const __half*)bufA, W1, b1, (__half*)bufB, N);  // bufB = h1h

    // ---- layers 2+3: block-coop gather@F=64 + relu(.@W2+b2)@W3*dinv, ONE kernel ----
    fused_g64_t2t3_kernel<<<cdiv(N / 32, 4), 256, 0, stream>>>(
        (const __half*)bufB, row_ptr, deg, csr_src, dinv, W2Th, b2, W3Th,
        (__half*)bufA, N);  // bufA = hw3h

    // ---- layer 3 aggregate at F=96 (+b3), XCD-sliced -> out ----
    gather96_slice_kernel<<<cdiv(N, 256) * 8, 256, 0, stream>>>(
        hdr, csr_src, (const __half*)bufA, b3, out, N);
}

// Round 10
// 450.317 us; speedup vs baseline: 1.4003x; 1.4003x over previous
//
#include <hip/hip_runtime.h>
#include <hip/hip_bf16.h>
#include <hip/hip_fp16.h>

// GCN 3-layer: x(N,12) -> 64 -> 128 -> 96, symmetric normalization + self loops.
// N=100000, E=1600000.
//
// R2: CSR + pull-gather (7028 -> 1364 us).           R3: 4x4-tile transform (-> 693).
// R4: aggregate at min-width 12/64/96, prescale (-> 550).
// R5/R6/R8: bucketed CSR build, nt stores, degree sort (-> 444).
// R9: fp16 feature rows for gathers (-> 382).
// R10: v_dot2_f32_f16 transforms + packed edge binning (-> 352).
// R11: layers 2+3 fused into ONE MFMA kernel; LPT gather order (-> 328).
// R12: unroll-8 index-prefetched gathers; fp16 layer-1 gather (neutral).
// R13/R14: csr_fill@1024, packed hdr (-> 324).
// R15: fused grid x2, hdr-in-dperm, gather_x+t1 fusion (-> 329, flat).
// R16: __launch_bounds__(256,2) on fused killed a 150MB accumulator spill (-> 289).
// R17: per-lane register gather fused into MFMA: REGRESSED (scratch + lost MLP).
// R18: block-cooperative g64+MFMA fusion (-> 276).
// R19: byte-sliced final gather: REGRESSED (-> 630). FETCH 1.23GB: slicing 24B
//      offsets within 192B rows has line-granular footprint = the WHOLE table
//      per XCD -> 8x compulsory traffic. Cache residency is 128B-line-granular.
// R20: SLICE-MAJOR storage. fused epilogue writes hw3s[s][N][12] (8 contiguous
//      2.4MB regions, byte-identical fp16 data). Each slice truly fits a 4MB
//      per-XCD L2; slice=blockIdx&7 pins slice->XCD (round-robin heuristic);
//      nontemporal hdr/csr loads keep the 64MB index streams from evicting the
//      resident slice. Same edge order -> bit-identical output.

static inline int cdiv(int a, int b) { return (a + b - 1) / b; }
constexpr int BLOCK = 256;
constexpr int BSHIFT = 9;                  // 512 nodes per bucket
constexpr int BNODES = 1 << BSHIFT;

typedef float nfloat4 __attribute__((ext_vector_type(4)));
typedef _Float16 f16x8 __attribute__((ext_vector_type(8)));
typedef float f32x16 __attribute__((ext_vector_type(16)));
typedef int iv4 __attribute__((ext_vector_type(4)));

// ---------------- small utils ----------------

__device__ __forceinline__ void nt_store_raw16(void* p, float4 v) {
    nfloat4 nv;
    nv.x = v.x; nv.y = v.y; nv.z = v.z; nv.w = v.w;
    __builtin_nontemporal_store(nv, (nfloat4*)p);
}

struct h4 { __half2 a, b; };  // 8 bytes = 4 fp16
__device__ __forceinline__ void store_h4(__half* p, float4 v) {
    h4 r;
    r.a = __floats2half2_rn(v.x, v.y);
    r.b = __floats2half2_rn(v.z, v.w);
    *(h4*)p = r;
}

// unpack 8 fp16 (one float4 raw load) and add into acc[0..7]
__device__ __forceinline__ void h8_add(float* acc, float4 raw) {
    union { float4 f; __half2 h[4]; } u;
    u.f = raw;
#pragma unroll
    for (int j = 0; j < 4; ++j) {
        float2 p = __half22float2(u.h[j]);
        acc[2 * j] += p.x;
        acc[2 * j + 1] += p.y;
    }
}

// unpack 4 fp16 (one float2 raw load) and add into acc[0..3]
__device__ __forceinline__ void h4_add(float* acc, float2 raw) {
    union { float2 f; __half2 h[2]; } u;
    u.f = raw;
    float2 p0 = __half22float2(u.h[0]);
    float2 p1 = __half22float2(u.h[1]);
    acc[0] += p0.x; acc[1] += p0.y; acc[2] += p1.x; acc[3] += p1.y;
}

__device__ __forceinline__ void h4_set(float* acc, float2 raw) {
    union { float2 f; __half2 h[2]; } u;
    u.f = raw;
    float2 p0 = __half22float2(u.h[0]);
    float2 p1 = __half22float2(u.h[1]);
    acc[0] = p0.x; acc[1] = p0.y; acc[2] = p1.x; acc[3] = p1.y;
}

// ---------------- CSR build (fully bucketed) ----------------

template <int CHUNK>
__global__ void bucket_count_kernel(const int* __restrict__ dst, int E,
                                    int* __restrict__ bcnt, int NB) {
    __shared__ int cnt[256];
    for (int i = threadIdx.x; i < NB; i += blockDim.x) cnt[i] = 0;
    __syncthreads();
    const int e0 = blockIdx.x * CHUNK;
    const int e1 = min(e0 + CHUNK, E);
    for (int e = e0 + threadIdx.x; e < e1; e += blockDim.x)
        atomicAdd(&cnt[dst[e] >> BSHIFT], 1);
    __syncthreads();
    for (int i = threadIdx.x; i < NB; i += blockDim.x)
        if (cnt[i]) atomicAdd(&bcnt[i], cnt[i]);
}

__global__ void bucket_scan_kernel(const int* __restrict__ bcnt, int* __restrict__ gbase,
                                   int* __restrict__ gcur, int NB) {
    __shared__ int tmp[256];
    int t = threadIdx.x;
    int v = (t < NB) ? bcnt[t] : 0;
    tmp[t] = v;
    __syncthreads();
    for (int off = 1; off < 256; off <<= 1) {
        int add = (t >= off) ? tmp[t - off] : 0;
        __syncthreads();
        tmp[t] += add;
        __syncthreads();
    }
    if (t < NB) { int ex = tmp[t] - v; gbase[t] = ex; gcur[t] = ex; }
}

// Phase A: bin edges by dst bucket; entry packed as s | (dst_local << 17)
template <int CHUNK>
__global__ void bin_edges_kernel(const int* __restrict__ ei, int E,
                                 int* __restrict__ gcur, unsigned* __restrict__ binned,
                                 int NB) {
    __shared__ int cnt[256], base[256], rk[256];
    for (int i = threadIdx.x; i < NB; i += blockDim.x) { cnt[i] = 0; rk[i] = 0; }
    __syncthreads();
    const int e0 = blockIdx.x * CHUNK;
    const int e1 = min(e0 + CHUNK, E);
    for (int e = e0 + threadIdx.x; e < e1; e += blockDim.x)
        atomicAdd(&cnt[ei[E + e] >> BSHIFT], 1);
    __syncthreads();
    for (int i = threadIdx.x; i < NB; i += blockDim.x)
        base[i] = atomicAdd(&gcur[i], cnt[i]);
    __syncthreads();
    for (int e = e0 + threadIdx.x; e < e1; e += blockDim.x) {
        int s = ei[e], d = ei[E + e];
        int b = d >> BSHIFT;
        int r = atomicAdd(&rk[b], 1);
        binned[base[b] + r] = (unsigned)s | ((unsigned)(d & (BNODES - 1)) << 17);
    }
}

// Phase B: one block per bucket, 1024 threads (16 waves). LDS degree hist +
// pair-scan on first 256 threads -> deg/dinv/row_ptr; scatter csr_src in
// L2-local window; 64-bin degree hist folded in.
__global__ void csr_fill_kernel(const int* __restrict__ gbase, const int* __restrict__ bcnt,
                                const unsigned* __restrict__ binned,
                                int* __restrict__ deg, float* __restrict__ dinv,
                                int* __restrict__ row_ptr, int* __restrict__ csr_src,
                                int* __restrict__ dh, int N) {
    __shared__ int c[BNODES];    // counts, then cursors
    __shared__ int ps[256];      // pair sums for scan
    __shared__ int dhloc[64];
    const int t = threadIdx.x;   // 0..1023
    const int b = blockIdx.x;
    const int node0 = b << BSHIFT;
    if (t < BNODES) c[t] = 0;
    if (t < 64) dhloc[t] = 0;
    __syncthreads();
    const int base = gbase[b];
    const int end = base + bcnt[b];
    for (int e = base + t; e < end; e += 1024)
        atomicAdd(&c[binned[e] >> 17], 1);
    __syncthreads();
    int s0 = 0, s1 = 0;
    if (t < 256) {
        s0 = c[2 * t]; s1 = c[2 * t + 1];
        ps[t] = s0 + s1;
    }
    __syncthreads();
    for (int off = 1; off < 256; off <<= 1) {
        int add = (t >= off && t < 256) ? ps[t - off] : 0;
        __syncthreads();
        if (t < 256) ps[t] += add;
        __syncthreads();
    }
    if (t < 256) {
        const int ex = ps[t] - (s0 + s1);
        const int p0 = base + ex;
        const int p1 = p0 + s0;
        const int n0 = node0 + 2 * t;
        if (n0 < N) {
            row_ptr[n0] = p0; deg[n0] = s0; dinv[n0] = rsqrtf((float)s0 + 1.0f);
            atomicAdd(&dhloc[min(s0, 63)], 1);
            if (n0 + 1 < N) {
                row_ptr[n0 + 1] = p1; deg[n0 + 1] = s1; dinv[n0 + 1] = rsqrtf((float)s1 + 1.0f);
                atomicAdd(&dhloc[min(s1, 63)], 1);
            }
        }
        c[2 * t] = p0; c[2 * t + 1] = p1;
    }
    __syncthreads();
    if (t < 64 && dhloc[t]) atomicAdd(&dh[t], dhloc[t]);
    for (int e = base + t; e < end; e += 1024) {
        unsigned sd = binned[e];
        int pos = atomicAdd(&c[sd >> 17], 1);
        csr_src[pos] = (int)(sd & 0x1FFFFu);
    }
}

// ---------------- degree counting sort (64 bins) -> packed headers ----------------

__global__ void dscan_kernel(int* __restrict__ dh) {
    __shared__ int tmp[64];
    int t = threadIdx.x;
    int v = dh[t];
    tmp[t] = v;
    __syncthreads();
    for (int off = 1; off < 64; off <<= 1) {
        int add = (t >= off) ? tmp[t - off] : 0;
        __syncthreads();
        tmp[t] += add;
        __syncthreads();
    }
    dh[t] = tmp[t] - v;
}

// counting-sort scatter that writes packed headers DIRECTLY. hdr[N-1-slot] =
// {row_ptr, deg, node, dinv_bits}: slot 0 = highest degree (LPT).
__global__ void dperm_kernel(const int* __restrict__ deg, const int* __restrict__ row_ptr,
                             const float* __restrict__ dinv, int* __restrict__ dh,
                             int4* __restrict__ hdr, int N) {
    __shared__ int cnt[64], base[64], rk[64];
    const int t = threadIdx.x;
    if (t < 64) { cnt[t] = 0; rk[t] = 0; }
    __syncthreads();
    const int i = blockIdx.x * blockDim.x + t;
    const int d = (i < N) ? deg[i] : 0;
    const int myb = (i < N) ? min(d, 63) : -1;
    if (myb >= 0) atomicAdd(&cnt[myb], 1);
    __syncthreads();
    if (t < 64) base[t] = cnt[t] ? atomicAdd(&dh[t], cnt[t]) : 0;
    __syncthreads();
    if (myb >= 0) {
        int r = atomicAdd(&rk[myb], 1);
        int slot = base[myb] + r;
        int4 h;
        h.x = row_ptr[i];
        h.y = d;
        h.z = i;
        h.w = __float_as_int(dinv[i]);
        hdr[N - 1 - slot] = h;
    }
}

// ---------------- prescale: x (N,12) f32 -> xs (N,16) f16, scaled by dinv ----

__global__ void prescale_h_kernel(const float* __restrict__ x, const float* __restrict__ dinv,
                                  __half* __restrict__ xs, int N) {
    int i = blockIdx.x * blockDim.x + threadIdx.x;
    if (i >= N) return;
    float di = dinv[i];
    const float4* xr = (const float4*)(x + (size_t)i * 12);
    float4 a = xr[0], b = xr[1], c = xr[2];
    union { float4 f; __half2 h[4]; } u0, u1;
    u0.h[0] = __floats2half2_rn(a.x * di, a.y * di);
    u0.h[1] = __floats2half2_rn(a.z * di, a.w * di);
    u0.h[2] = __floats2half2_rn(b.x * di, b.y * di);
    u0.h[3] = __floats2half2_rn(b.z * di, b.w * di);
    u1.h[0] = __floats2half2_rn(c.x * di, c.y * di);
    u1.h[1] = __floats2half2_rn(c.z * di, c.w * di);
    u1.h[2] = __floats2half2_rn(0.f, 0.f);
    u1.h[3] = __floats2half2_rn(0.f, 0.f);
    float4* op = (float4*)(xs + (size_t)i * 16);
    op[0] = u0.f;
    op[1] = u1.f;
}

// ---------------- fused gather_x + transform-1 ----------------

// Phase 1: aggregate xs (fp16 [N][16], prescaled) at F=16h, 2 threads/node,
// results (scaled by dinv) into LDS xrow[128][12].  Phase 2: 12->64 transform
// from LDS-resident W1 (+b1, relu, *dinv) -> h1h fp16 rows.
__global__ void gather_x_t1_kernel(const int4* __restrict__ hdr,
                                   const int* __restrict__ csr_src,
                                   const __half* __restrict__ xs,
                                   const float* __restrict__ W1,
                                   const float* __restrict__ b1,
                                   __half* __restrict__ h1h, int N) {
    __shared__ float W1s[12 * 64];    // 3 KB
    __shared__ float xrow[128][12];   // 6 KB
    const int tid = threadIdx.x;
    for (int u = tid; u < 12 * 64 / 4; u += 256)
        ((float4*)W1s)[u] = ((const float4*)W1)[u];

    const int t = blockIdx.x * 256 + tid;
    const bool valid = (t < N * 2);
    const int slot = t >> 1;
    const int c = t & 1;
    const int nl = tid >> 1;
    int4 H = valid ? hdr[slot] : make_int4(0, 0, 0, 0);
    const int* __restrict__ sp = csr_src + H.x;
    const int n = valid ? H.y : 0;
    const int i = H.z;
    const float di = __int_as_float(H.w);
    const int f0 = c * 8;

    float acc[8];
    {
        union { float4 f; __half2 h[4]; } u;
        u.f = *(const float4*)(xs + (size_t)i * 16 + f0);  // self loop
#pragma unroll
        for (int j = 0; j < 4; ++j) {
            float2 p = __half22float2(u.h[j]);
            acc[2 * j] = p.x; acc[2 * j + 1] = p.y;
        }
    }

    int k = 0;
    if (n >= 8) {
        int s[8];
#pragma unroll
        for (int j = 0; j < 8; ++j) s[j] = sp[j];
        for (; k + 16 <= n; k += 8) {
            int ns[8];
#pragma unroll
            for (int j = 0; j < 8; ++j) ns[j] = sp[k + 8 + j];
            float4 v[8];
#pragma unroll
            for (int j = 0; j < 8; ++j) v[j] = *(const float4*)(xs + (size_t)s[j] * 16 + f0);
#pragma unroll
            for (int j = 0; j < 8; ++j) h8_add(acc, v[j]);
#pragma unroll
            for (int j = 0; j < 8; ++j) s[j] = ns[j];
        }
        float4 v[8];
#pragma unroll
        for (int j = 0; j < 8; ++j) v[j] = *(const float4*)(xs + (size_t)s[j] * 16 + f0);
#pragma unroll
        for (int j = 0; j < 8; ++j) h8_add(acc, v[j]);
        k += 8;
    }
    for (; k + 4 <= n; k += 4) {
        int s0 = sp[k + 0], s1 = sp[k + 1], s2 = sp[k + 2], s3 = sp[k + 3];
        float4 v0 = *(const float4*)(xs + (size_t)s0 * 16 + f0);
        float4 v1 = *(const float4*)(xs + (size_t)s1 * 16 + f0);
        float4 v2 = *(const float4*)(xs + (size_t)s2 * 16 + f0);
        float4 v3 = *(const float4*)(xs + (size_t)s3 * 16 + f0);
        h8_add(acc, v0); h8_add(acc, v1); h8_add(acc, v2); h8_add(acc, v3);
    }
    for (; k < n; ++k) {
        float4 v = *(const float4*)(xs + (size_t)sp[k] * 16 + f0);
        h8_add(acc, v);
    }

    if (valid) {
        if (c == 0) {
#pragma unroll
            for (int j = 0; j < 8; ++j) xrow[nl][j] = acc[j] * di;
        } else {
#pragma unroll
            for (int j = 0; j < 4; ++j) xrow[nl][8 + j] = acc[j] * di;  // f 8..11
        }
    }
    __syncthreads();
    if (!valid) return;

    float xr[12];
#pragma unroll
    for (int j = 0; j < 12; ++j) xr[j] = xrow[nl][j];

    __half* op = h1h + (size_t)i * 64 + c * 32;
#pragma unroll
    for (int g = 0; g < 8; ++g) {
        const int c0 = c * 32 + g * 4;
        float4 r = *(const float4*)(b1 + c0);
#pragma unroll
        for (int kk = 0; kk < 12; ++kk) {
            const float4 w = *(const float4*)(W1s + kk * 64 + c0);
            r.x = fmaf(xr[kk], w.x, r.x);
            r.y = fmaf(xr[kk], w.y, r.y);
            r.z = fmaf(xr[kk], w.z, r.z);
            r.w = fmaf(xr[kk], w.w, r.w);
        }
        r.x = fmaxf(r.x, 0.f) * di; r.y = fmaxf(r.y, 0.f) * di;
        r.z = fmaxf(r.z, 0.f) * di; r.w = fmaxf(r.w, 0.f) * di;
        store_h4(op + g * 4, r);
    }
}

// ---------------- fused gather64 (block-coop) + MFMA layers 2+3 ----------------

// prep: W2 (64x128 f32, k-major) -> W2T (128x64 f16, n-major);
//       W3 (128x96 f32)          -> W3T (96x128 f16, n-major).
__global__ void prep_w_kernel(const float* __restrict__ W2, const float* __restrict__ W3,
                              __half* __restrict__ W2T, __half* __restrict__ W3T) {
    int i = blockIdx.x * 256 + threadIdx.x;
    if (i < 64 * 128) {
        int k = i >> 7, n = i & 127;
        W2T[n * 64 + k] = __float2half(W2[i]);
    } else {
        int j = i - 64 * 128;
        if (j < 128 * 96) {
            int k = j / 96, n = j - k * 96;
            W3T[n * 128 + k] = __float2half(W3[j]);
        }
    }
}

// Block handles 4 tiles (128 rows), 1 per wave.
// Phase 1 (block-wide): PROVEN gather64 loop -> agg rows (fp16,*dinv) into LDS.
// Phase 2 (per wave): PROVEN t2/t3 MFMA path; h2 OVERLAYS agg region.
// Epilogue (R20): SLICE-MAJOR store — hw3s[s][N][12] fp16: per (tile,slice) a
// contiguous 768B region; chunk w (16B) spans <=2 LDS rows (2x 8B reads).
// Frag layouts (gfx950, guide-verified):
//   A: lane holds A[row=l&31][k = kb*16 + (l>>5)*8 + j], j=0..7
//   B: lane holds B[k = kb*16 + (l>>5)*8 + j][col=l&31]  (n-major W^T rows)
//   C/D: elem r -> row = (r&3) + 8*(r>>2) + 4*(l>>5), col = l&31
// LB(256,2): 256-VGPR cap (spill-proof); LDS 34.8KB -> 4 blocks/CU.
__global__ void __launch_bounds__(256, 2)
fused_g64_t2t3_kernel(const __half* __restrict__ h1h,   // [N][64] f16 (pre-scaled rows)
                      const int* __restrict__ row_ptr, const int* __restrict__ deg,
                      const int* __restrict__ csr_src, const float* __restrict__ dinv,
                      const __half* __restrict__ W2T,   // [128][64] f16
                      const float* __restrict__ b2,     // [128]
                      const __half* __restrict__ W3T,   // [96][128] f16
                      __half* __restrict__ hw3s,        // [8][N][12] f16 slice-major
                      int N) {
    constexpr int LDH = 136;  // halves; 272B rows: 16B-aligned
    __shared__ _Float16 buf[4][32 * LDH];  // agg tiles, overlaid by h2 in phase 2
    const int tid = threadIdx.x;
    const int lane = tid & 63;
    const int wid = tid >> 6;
    const int l31 = lane & 31;
    const int lh = lane >> 5;  // 0/1
    const int NT = N >> 5;     // N % 32 == 0
    const int t0 = blockIdx.x * 4;

    // ---- phase 1: block-cooperative gather64 into LDS ----
    {
        const int nr = tid >> 3;        // node-row within tile (0..31)
        const int f0 = (tid & 7) * 8;   // feature start (halves)
#pragma unroll 1
        for (int p = 0; p < 4; ++p) {
            const int t = t0 + p;       // block-uniform
            if (t >= NT) break;
            const int i = (t << 5) + nr;
            const int* __restrict__ sp = csr_src + row_ptr[i];
            const int n = deg[i];
            const float di = dinv[i];

            float acc[8];
            {
                union { float4 f; __half2 h[4]; } u;
                u.f = *(const float4*)(h1h + (size_t)i * 64 + f0);  // self loop
#pragma unroll
                for (int j = 0; j < 4; ++j) {
                    float2 pp = __half22float2(u.h[j]);
                    acc[2 * j] = pp.x; acc[2 * j + 1] = pp.y;
                }
            }

            int k = 0;
            if (n >= 8) {
                int s[8];
#pragma unroll
                for (int j = 0; j < 8; ++j) s[j] = sp[j];
                for (; k + 16 <= n; k += 8) {
                    int ns[8];
#pragma unroll
                    for (int j = 0; j < 8; ++j) ns[j] = sp[k + 8 + j];
                    float4 v[8];
#pragma unroll
                    for (int j = 0; j < 8; ++j) v[j] = *(const float4*)(h1h + (size_t)s[j] * 64 + f0);
#pragma unroll
                    for (int j = 0; j < 8; ++j) h8_add(acc, v[j]);
#pragma unroll
                    for (int j = 0; j < 8; ++j) s[j] = ns[j];
                }
                float4 v[8];
#pragma unroll
                for (int j = 0; j < 8; ++j) v[j] = *(const float4*)(h1h + (size_t)s[j] * 64 + f0);
#pragma unroll
                for (int j = 0; j < 8; ++j) h8_add(acc, v[j]);
                k += 8;
            }
            for (; k + 4 <= n; k += 4) {
                int s0 = sp[k + 0], s1 = sp[k + 1], s2 = sp[k + 2], s3 = sp[k + 3];
                float4 v0 = *(const float4*)(h1h + (size_t)s0 * 64 + f0);
                float4 v1 = *(const float4*)(h1h + (size_t)s1 * 64 + f0);
                float4 v2 = *(const float4*)(h1h + (size_t)s2 * 64 + f0);
                float4 v3 = *(const float4*)(h1h + (size_t)s3 * 64 + f0);
                h8_add(acc, v0); h8_add(acc, v1); h8_add(acc, v2); h8_add(acc, v3);
            }
            for (; k < n; ++k) {
                float4 v = *(const float4*)(h1h + (size_t)sp[k] * 64 + f0);
                h8_add(acc, v);
            }

            union { float4 f; __half2 h[4]; } o;
            o.h[0] = __floats2half2_rn(acc[0] * di, acc[1] * di);
            o.h[1] = __floats2half2_rn(acc[2] * di, acc[3] * di);
            o.h[2] = __floats2half2_rn(acc[4] * di, acc[5] * di);
            o.h[3] = __floats2half2_rn(acc[6] * di, acc[7] * di);
            *(float4*)(&buf[p][nr * LDH + f0]) = o.f;
        }
    }
    __syncthreads();

    // ---- phase 2: per-wave t2/t3 MFMA on tile t0+wid ----
    const int t = t0 + wid;
    if (t >= NT) return;
    const int r0 = t << 5;
    _Float16* hs = buf[wid];

    float b2v[4];
#pragma unroll
    for (int nt = 0; nt < 4; ++nt) b2v[nt] = b2[nt * 32 + l31];

    // A-frags from LDS (agg rows), fully register-buffered before overwrite
    f16x8 a2[4];
#pragma unroll
    for (int kb = 0; kb < 4; ++kb)
        a2[kb] = *(const f16x8*)(hs + l31 * LDH + kb * 16 + lh * 8);

    // ---- t2 ----
#pragma unroll
    for (int nt = 0; nt < 4; ++nt) {
        f32x16 c = {0.f, 0.f, 0.f, 0.f, 0.f, 0.f, 0.f, 0.f,
                    0.f, 0.f, 0.f, 0.f, 0.f, 0.f, 0.f, 0.f};
#pragma unroll
        for (int kb = 0; kb < 4; ++kb) {
            f16x8 b = *(const f16x8*)(W2T + (size_t)(nt * 32 + l31) * 64 + kb * 16 + lh * 8);
            c = __builtin_amdgcn_mfma_f32_32x32x16_f16(a2[kb], b, c, 0, 0, 0);
        }
#pragma unroll
        for (int r = 0; r < 16; ++r) {
            int row = (r & 3) + 8 * (r >> 2) + 4 * lh;
            float v = fmaxf(c[r] + b2v[nt], 0.f);
            hs[row * LDH + nt * 32 + l31] = (_Float16)v;
        }
    }

    // ---- t3 ----
    f16x8 a3[8];
#pragma unroll
    for (int kb = 0; kb < 8; ++kb)
        a3[kb] = *(const f16x8*)(hs + l31 * LDH + kb * 16 + lh * 8);
    float4 dv[4];
#pragma unroll
    for (int rg = 0; rg < 4; ++rg)
        dv[rg] = *(const float4*)(dinv + r0 + rg * 8 + lh * 4);
#pragma unroll
    for (int nt = 0; nt < 3; ++nt) {
        f32x16 c = {0.f, 0.f, 0.f, 0.f, 0.f, 0.f, 0.f, 0.f,
                    0.f, 0.f, 0.f, 0.f, 0.f, 0.f, 0.f, 0.f};
#pragma unroll
        for (int kb = 0; kb < 8; ++kb) {
            f16x8 b = *(const f16x8*)(W3T + (size_t)(nt * 32 + l31) * 128 + kb * 16 + lh * 8);
            c = __builtin_amdgcn_mfma_f32_32x32x16_f16(a3[kb], b, c, 0, 0, 0);
        }
#pragma unroll
        for (int r = 0; r < 16; ++r) {
            int row = (r & 3) + 8 * (r >> 2) + 4 * lh;
            float dvv = ((const float*)&dv[r >> 2])[r & 3];
            hs[row * LDH + nt * 32 + l31] = (_Float16)(c[r] * dvv);
        }
    }

    // ---- SLICE-MAJOR out store: 8 slices x 768B contiguous per tile ----
    // id in [0,384): slice = id/48, chunk w = id%48 covers bytes [16w,16w+16)
    // of the 32x24B region; a chunk spans <=2 LDS rows -> two 8B reads.
    {
        const size_t sstride = (size_t)N * 24;  // bytes per slice region
        char* ob = (char*)hw3s;
        const char* hb = (const char*)hs;
#pragma unroll
        for (int it = 0; it < 6; ++it) {
            int id = lane + it * 64;
            int s = id / 48;
            int w = id - s * 48;
            int b0 = w * 16, b1 = b0 + 8;
            int ra = b0 / 24, oa = b0 - ra * 24;
            int rb = b1 / 24, ob2 = b1 - rb * 24;
            float2 v0 = *(const float2*)(hb + ra * (LDH * 2) + s * 24 + oa);
            float2 v1 = *(const float2*)(hb + rb * (LDH * 2) + s * 24 + ob2);
            float4 v = make_float4(v0.x, v0.y, v1.x, v1.y);
            *(float4*)(ob + (size_t)s * sstride + (size_t)r0 * 24 + b0) = v;
        }
    }
}

// ---------------- XCD-sliced final gather (slice-major table) ----------------

// slice = blockIdx&7 -> pinned to one XCD (round-robin heuristic). Slice table
// hw3s[s] is CONTIGUOUS 2.4MB (N rows x 24B) -> truly L2-resident per XCD.
// Nontemporal hdr/csr loads keep the streamed indices from evicting it.
// One thread per node per slice: 12 features, 3x float2/edge, fp32 accum in
// identical edge order -> bit-identical results.
__global__ void __launch_bounds__(256)
gather96_slice_kernel(const int4* __restrict__ hdr, const int* __restrict__ csr_src,
                      const __half* __restrict__ hw3s, const float* __restrict__ b,
                      float* __restrict__ out, int N) {
    const int bid = blockIdx.x;
    const int slice = bid & 7;
    const int slot = (bid >> 3) * 256 + threadIdx.x;
    if (slot >= N) return;
    const iv4 H = __builtin_nontemporal_load((const iv4*)(hdr + slot));
    const int* __restrict__ sp = csr_src + H[0];
    const int n = H[1];
    const int i = H[2];
    const float di = __int_as_float(H[3]);
    const char* __restrict__ tb = (const char*)hw3s + (size_t)slice * N * 24;

    float acc[12];
    {
        const char* rp = tb + (size_t)i * 24;  // self loop
        h4_set(acc + 0, *(const float2*)(rp));
        h4_set(acc + 4, *(const float2*)(rp + 8));
        h4_set(acc + 8, *(const float2*)(rp + 16));
    }

    int k = 0;
    if (n >= 8) {
        int s[8];
#pragma unroll
        for (int j = 0; j < 8; ++j) s[j] = __builtin_nontemporal_load(sp + j);
        for (; k + 16 <= n; k += 8) {
            int ns[8];
#pragma unroll
            for (int j = 0; j < 8; ++j) ns[j] = __builtin_nontemporal_load(sp + k + 8 + j);
#pragma unroll
            for (int j = 0; j < 8; ++j) {
                const char* p = tb + (size_t)s[j] * 24;
                h4_add(acc + 0, *(const float2*)(p));
                h4_add(acc + 4, *(const float2*)(p + 8));
                h4_add(acc + 8, *(const float2*)(p + 16));
            }
#pragma unroll
            for (int j = 0; j < 8; ++j) s[j] = ns[j];
        }
#pragma unroll
        for (int j = 0; j < 8; ++j) {
            const char* p = tb + (size_t)s[j] * 24;
            h4_add(acc + 0, *(const float2*)(p));
            h4_add(acc + 4, *(const float2*)(p + 8));
            h4_add(acc + 8, *(const float2*)(p + 16));
        }
        k += 8;
    }
    for (; k < n; ++k) {
        const char* p = tb + (size_t)__builtin_nontemporal_load(sp + k) * 24;
        h4_add(acc + 0, *(const float2*)(p));
        h4_add(acc + 4, *(const float2*)(p + 8));
        h4_add(acc + 8, *(const float2*)(p + 16));
    }

    const float4 bb0 = *(const float4*)(b + slice * 12);
    const float4 bb1 = *(const float4*)(b + slice * 12 + 4);
    const float4 bb2 = *(const float4*)(b + slice * 12 + 8);
    float4 r0, r1, r2;
    r0.x = fmaf(acc[0], di, bb0.x); r0.y = fmaf(acc[1], di, bb0.y);
    r0.z = fmaf(acc[2], di, bb0.z); r0.w = fmaf(acc[3], di, bb0.w);
    r1.x = fmaf(acc[4], di, bb1.x); r1.y = fmaf(acc[5], di, bb1.y);
    r1.z = fmaf(acc[6], di, bb1.z); r1.w = fmaf(acc[7], di, bb1.w);
    r2.x = fmaf(acc[8], di, bb2.x); r2.y = fmaf(acc[9], di, bb2.y);
    r2.z = fmaf(acc[10], di, bb2.z); r2.w = fmaf(acc[11], di, bb2.w);
    float* op = out + (size_t)i * 96 + slice * 12;
    nt_store_raw16(op, r0);
    nt_store_raw16(op + 4, r1);
    nt_store_raw16(op + 8, r2);
}

// ---------------- launch ----------------

extern "C" void kernel_launch(void* const* d_in, const int* in_sizes, int n_in,
                              void* d_out, int out_size, void* d_ws, size_t ws_size,
                              hipStream_t stream) {
    const float* x  = (const float*)d_in[0];
    const int*   ei = (const int*)d_in[1];  // (2,E): row0=src, row1=dst
    const float* W1 = (const float*)d_in[2];
    const float* b1 = (const float*)d_in[3];
    const float* W2 = (const float*)d_in[4];
    const float* b2 = (const float*)d_in[5];
    const float* W3 = (const float*)d_in[6];
    const float* b3 = (const float*)d_in[7];
    float* out = (float*)d_out;

    const int N = in_sizes[0] / 12;
    const int E = in_sizes[1] / 2;
    const int NB = cdiv(N, BNODES);  // 196 dst buckets (<=256)

    // workspace layout
    char* ws = (char*)d_ws;
    int*   deg     = (int*)ws;    ws += (size_t)N * sizeof(int);
    int*   row_ptr = (int*)ws;    ws += (size_t)N * sizeof(int);
    int*   bcnt    = (int*)ws;    ws += 256 * sizeof(int);
    int*   dh      = (int*)ws;    ws += 64 * sizeof(int);
    int*   gbase   = (int*)ws;    ws += 256 * sizeof(int);
    int*   gcur    = (int*)ws;    ws += 256 * sizeof(int);
    float* dinv    = (float*)ws;  ws += (size_t)N * sizeof(float);
    int4*  hdr     = (int4*)ws;   ws += (size_t)N * sizeof(int4);
    __half* W2Th   = (__half*)ws; ws += 128 * 64 * sizeof(__half);
    __half* W3Th   = (__half*)ws; ws += 96 * 128 * sizeof(__half);
    int*   csr_src = (int*)ws;    ws += (size_t)E * sizeof(int);
    float* bufA    = (float*)ws;  ws += (size_t)N * 128 * sizeof(float);  // xs / hw3s
    float* bufB    = (float*)ws;                                          // binned / h1h
    unsigned* binned = (unsigned*)bufB;  // aliased: consumed before bufB reused

    // ---- CSR build (fully bucketed) + weight prep ----
    hipMemsetAsync(bcnt, 0, (256 + 64) * sizeof(int), stream);  // bcnt + dh (contiguous)
    prep_w_kernel<<<80, 256, 0, stream>>>(W2, W3, W2Th, W3Th);
    bucket_count_kernel<8192><<<cdiv(E, 8192), BLOCK, 0, stream>>>(ei + E, E, bcnt, NB);
    bucket_scan_kernel<<<1, 256, 0, stream>>>(bcnt, gbase, gcur, NB);
    bin_edges_kernel<8192><<<cdiv(E, 8192), BLOCK, 0, stream>>>(ei, E, gcur, binned, NB);
    csr_fill_kernel<<<NB, 1024, 0, stream>>>(gbase, bcnt, binned, deg, dinv, row_ptr,
                                             csr_src, dh, N);

    // ---- degree counting sort -> packed headers ----
    dscan_kernel<<<1, 64, 0, stream>>>(dh);
    dperm_kernel<<<cdiv(N, BLOCK), BLOCK, 0, stream>>>(deg, row_ptr, dinv, dh, hdr, N);

    // ---- layer 1: prescale->fp16, fused aggregate@F=16h + 12->64 transform ----
    prescale_h_kernel<<<cdiv(N, BLOCK), BLOCK, 0, stream>>>(x, dinv, (__half*)bufA, N);
    gather_x_t1_kernel<<<cdiv(N * 2, BLOCK), BLOCK, 0, stream>>>(
        hdr, csr_src, (const __half*)bufA, W1, b1, (__half*)bufB, N);  // bufB = h1h

    // ---- layers 2+3: block-coop gather@F=64 + relu(.@W2+b2)@W3*dinv, ONE kernel ----
    fused_g64_t2t3_kernel<<<cdiv(N / 32, 4), 256, 0, stream>>>(
        (const __half*)bufB, row_ptr, deg, csr_src, dinv, W2Th, b2, W3Th,
        (__half*)bufA, N);  // bufA = hw3s (slice-major [8][N][12])

    // ---- layer 3 aggregate at F=96 (+b3), XCD-sliced -> out ----
    gather96_slice_kernel<<<cdiv(N, 256) * 8, 256, 0, stream>>>(
        hdr, csr_src, (const __half*)bufA, b3, out, N);
}

// Round 11
// 273.514 us; speedup vs baseline: 2.3055x; 1.6464x over previous
//
#include <hip/hip_runtime.h>
#include <hip/hip_bf16.h>
#include <hip/hip_fp16.h>

// GCN 3-layer: x(N,12) -> 64 -> 128 -> 96, symmetric normalization + self loops.
// N=100000, E=1600000.
//
// R2: CSR + pull-gather (7028 -> 1364 us).           R3: 4x4-tile transform (-> 693).
// R4: aggregate at min-width 12/64/96, prescale (-> 550).
// R5/R6/R8: bucketed CSR build, nt stores, degree sort (-> 444).
// R9: fp16 feature rows for gathers (-> 382).
// R10: v_dot2_f32_f16 transforms + packed edge binning (-> 352).
// R11: layers 2+3 fused into ONE MFMA kernel; LPT gather order (-> 328).
// R12: unroll-8 index-prefetched gathers (neutral: gathers are miss-path bound).
// R13/R14: csr_fill@1024, packed hdr (-> 324).
// R16: __launch_bounds__(256,2) on fused killed a 150MB accumulator spill (-> 289).
// R17: per-lane register gather fused into MFMA: REGRESSED (scratch + lost MLP).
// R18: block-cooperative g64+MFMA fusion (-> 276).
// R19/R20: XCD slice-pinning of the final gather: REGRESSED both ways (630/450).
//      Even slice-major 2.4MB tables don't become XCD-L2-resident via the
//      blockIdx&7 heuristic. Random-gather service (~4 TB/s miss path) is a
//      structural floor. Direction abandoned; reverted to R18.
// R21: R18 + launch-count trim: bucket_scan & dscan folded into consumers
//      (each block recomputes the <=256-elem exclusive scan locally in LDS;
//      zero-init global cursors give cross-block ranks; identical positions).

static inline int cdiv(int a, int b) { return (a + b - 1) / b; }
constexpr int BLOCK = 256;
constexpr int BSHIFT = 9;                  // 512 nodes per bucket
constexpr int BNODES = 1 << BSHIFT;

typedef float nfloat4 __attribute__((ext_vector_type(4)));
typedef _Float16 f16x8 __attribute__((ext_vector_type(8)));
typedef float f32x16 __attribute__((ext_vector_type(16)));

// ---------------- small utils ----------------

__device__ __forceinline__ void nt_store_raw16(void* p, float4 v) {
    nfloat4 nv;
    nv.x = v.x; nv.y = v.y; nv.z = v.z; nv.w = v.w;
    __builtin_nontemporal_store(nv, (nfloat4*)p);
}

struct h4 { __half2 a, b; };  // 8 bytes = 4 fp16
__device__ __forceinline__ void store_h4(__half* p, float4 v) {
    h4 r;
    r.a = __floats2half2_rn(v.x, v.y);
    r.b = __floats2half2_rn(v.z, v.w);
    *(h4*)p = r;
}

// unpack 8 fp16 (one float4 raw load) and add into acc[0..7]
__device__ __forceinline__ void h8_add(float* acc, float4 raw) {
    union { float4 f; __half2 h[4]; } u;
    u.f = raw;
#pragma unroll
    for (int j = 0; j < 4; ++j) {
        float2 p = __half22float2(u.h[j]);
        acc[2 * j] += p.x;
        acc[2 * j + 1] += p.y;
    }
}

// ---------------- CSR build (fully bucketed) ----------------

template <int CHUNK>
__global__ void bucket_count_kernel(const int* __restrict__ dst, int E,
                                    int* __restrict__ bcnt, int NB) {
    __shared__ int cnt[256];
    for (int i = threadIdx.x; i < NB; i += blockDim.x) cnt[i] = 0;
    __syncthreads();
    const int e0 = blockIdx.x * CHUNK;
    const int e1 = min(e0 + CHUNK, E);
    for (int e = e0 + threadIdx.x; e < e1; e += blockDim.x)
        atomicAdd(&cnt[dst[e] >> BSHIFT], 1);
    __syncthreads();
    for (int i = threadIdx.x; i < NB; i += blockDim.x)
        if (cnt[i]) atomicAdd(&bcnt[i], cnt[i]);
}

// Phase A: bin edges by dst bucket; entry packed as s | (dst_local << 17).
// R21: bucket base = LOCAL exclusive scan of bcnt (complete before this
// kernel) + zero-init global cursor gcur -> same positions as the old
// separate bucket_scan kernel.
template <int CHUNK>
__global__ void bin_edges_kernel(const int* __restrict__ ei, int E,
                                 const int* __restrict__ bcnt,
                                 int* __restrict__ gcur, unsigned* __restrict__ binned,
                                 int NB) {
    __shared__ int cnt[256], base[256], rk[256], sc[256];
    const int t = threadIdx.x;
    const int bv = (t < NB) ? bcnt[t] : 0;
    sc[t] = bv;
    for (int i = t; i < NB; i += blockDim.x) { cnt[i] = 0; rk[i] = 0; }
    __syncthreads();
    for (int off = 1; off < 256; off <<= 1) {
        int add = (t >= off) ? sc[t - off] : 0;
        __syncthreads();
        sc[t] += add;
        __syncthreads();
    }
    const int ex = sc[t] - bv;  // exclusive scan of bcnt at t
    const int e0 = blockIdx.x * CHUNK;
    const int e1 = min(e0 + CHUNK, E);
    for (int e = e0 + t; e < e1; e += blockDim.x)
        atomicAdd(&cnt[ei[E + e] >> BSHIFT], 1);
    __syncthreads();
    if (t < NB) base[t] = ex + (cnt[t] ? atomicAdd(&gcur[t], cnt[t]) : 0);
    __syncthreads();
    for (int e = e0 + t; e < e1; e += blockDim.x) {
        int s = ei[e], d = ei[E + e];
        int b = d >> BSHIFT;
        int r = atomicAdd(&rk[b], 1);
        binned[base[b] + r] = (unsigned)s | ((unsigned)(d & (BNODES - 1)) << 17);
    }
}

// Phase B: one block per bucket, 1024 threads (16 waves). LDS degree hist +
// pair-scan on first 256 threads -> deg/dinv/row_ptr; scatter csr_src in
// L2-local window; 64-bin degree hist folded in.
// R21: bucket base via local scan of bcnt (no gbase array).
__global__ void csr_fill_kernel(const int* __restrict__ bcnt,
                                const unsigned* __restrict__ binned,
                                int* __restrict__ deg, float* __restrict__ dinv,
                                int* __restrict__ row_ptr, int* __restrict__ csr_src,
                                int* __restrict__ dh, int N) {
    __shared__ int c[BNODES];    // counts, then cursors
    __shared__ int ps[256];      // scans
    __shared__ int dhloc[64];
    __shared__ int sbase;
    const int t = threadIdx.x;   // 0..1023
    const int b = blockIdx.x;
    const int node0 = b << BSHIFT;
    if (t < BNODES) c[t] = 0;
    if (t < 64) dhloc[t] = 0;
    if (t < 256) ps[t] = bcnt[t];
    __syncthreads();
    for (int off = 1; off < 256; off <<= 1) {
        int add = (t >= off && t < 256) ? ps[t - off] : 0;
        __syncthreads();
        if (t < 256) ps[t] += add;
        __syncthreads();
    }
    if (t == 0) sbase = (b == 0) ? 0 : ps[b - 1];
    __syncthreads();
    const int base = sbase;
    const int end = base + bcnt[b];
    for (int e = base + t; e < end; e += 1024)
        atomicAdd(&c[binned[e] >> 17], 1);
    __syncthreads();
    int s0 = 0, s1 = 0;
    if (t < 256) {
        s0 = c[2 * t]; s1 = c[2 * t + 1];
        ps[t] = s0 + s1;
    }
    __syncthreads();
    for (int off = 1; off < 256; off <<= 1) {
        int add = (t >= off && t < 256) ? ps[t - off] : 0;
        __syncthreads();
        if (t < 256) ps[t] += add;
        __syncthreads();
    }
    if (t < 256) {
        const int ex = ps[t] - (s0 + s1);
        const int p0 = base + ex;
        const int p1 = p0 + s0;
        const int n0 = node0 + 2 * t;
        if (n0 < N) {
            row_ptr[n0] = p0; deg[n0] = s0; dinv[n0] = rsqrtf((float)s0 + 1.0f);
            atomicAdd(&dhloc[min(s0, 63)], 1);
            if (n0 + 1 < N) {
                row_ptr[n0 + 1] = p1; deg[n0 + 1] = s1; dinv[n0 + 1] = rsqrtf((float)s1 + 1.0f);
                atomicAdd(&dhloc[min(s1, 63)], 1);
            }
        }
        c[2 * t] = p0; c[2 * t + 1] = p1;
    }
    __syncthreads();
    if (t < 64 && dhloc[t]) atomicAdd(&dh[t], dhloc[t]);
    for (int e = base + t; e < end; e += 1024) {
        unsigned sd = binned[e];
        int pos = atomicAdd(&c[sd >> 17], 1);
        csr_src[pos] = (int)(sd & 0x1FFFFu);
    }
}

// ---------------- degree counting sort (64 bins) -> packed headers ----------------

// R21: dscan folded in — each block computes the 64-bin exclusive scan of dh
// (counts, complete after csr_fill) locally; zero-init cursor dcur gives
// cross-block ranks. hdr[N-1-slot] = {row_ptr, deg, node, dinv_bits}:
// slot 0 = highest degree (LPT).
__global__ void dperm_kernel(const int* __restrict__ deg, const int* __restrict__ row_ptr,
                             const float* __restrict__ dinv, const int* __restrict__ dh,
                             int* __restrict__ dcur, int4* __restrict__ hdr, int N) {
    __shared__ int cnt[64], base[64], rk[64], sc[64];
    const int t = threadIdx.x;
    if (t < 64) {
        cnt[t] = 0; rk[t] = 0;
        sc[t] = dh[t];
    }
    __syncthreads();
    for (int off = 1; off < 64; off <<= 1) {
        int add = (t >= off && t < 64) ? sc[t - off] : 0;
        __syncthreads();
        if (t < 64) sc[t] += add;
        __syncthreads();
    }
    const int i = blockIdx.x * blockDim.x + t;
    const int d = (i < N) ? deg[i] : 0;
    const int myb = (i < N) ? min(d, 63) : -1;
    if (myb >= 0) atomicAdd(&cnt[myb], 1);
    __syncthreads();
    if (t < 64) {
        const int ex = sc[t] - dh[t];
        base[t] = ex + (cnt[t] ? atomicAdd(&dcur[t], cnt[t]) : 0);
    }
    __syncthreads();
    if (myb >= 0) {
        int r = atomicAdd(&rk[myb], 1);
        int slot = base[myb] + r;
        int4 h;
        h.x = row_ptr[i];
        h.y = d;
        h.z = i;
        h.w = __float_as_int(dinv[i]);
        hdr[N - 1 - slot] = h;
    }
}

// ---------------- prescale: x (N,12) f32 -> xs (N,16) f16, scaled by dinv ----

__global__ void prescale_h_kernel(const float* __restrict__ x, const float* __restrict__ dinv,
                                  __half* __restrict__ xs, int N) {
    int i = blockIdx.x * blockDim.x + threadIdx.x;
    if (i >= N) return;
    float di = dinv[i];
    const float4* xr = (const float4*)(x + (size_t)i * 12);
    float4 a = xr[0], b = xr[1], c = xr[2];
    union { float4 f; __half2 h[4]; } u0, u1;
    u0.h[0] = __floats2half2_rn(a.x * di, a.y * di);
    u0.h[1] = __floats2half2_rn(a.z * di, a.w * di);
    u0.h[2] = __floats2half2_rn(b.x * di, b.y * di);
    u0.h[3] = __floats2half2_rn(b.z * di, b.w * di);
    u1.h[0] = __floats2half2_rn(c.x * di, c.y * di);
    u1.h[1] = __floats2half2_rn(c.z * di, c.w * di);
    u1.h[2] = __floats2half2_rn(0.f, 0.f);
    u1.h[3] = __floats2half2_rn(0.f, 0.f);
    float4* op = (float4*)(xs + (size_t)i * 16);
    op[0] = u0.f;
    op[1] = u1.f;
}

// ---------------- fused gather_x + transform-1 ----------------

// Phase 1: aggregate xs (fp16 [N][16], prescaled) at F=16h, 2 threads/node,
// results (scaled by dinv) into LDS xrow[128][12].  Phase 2: 12->64 transform
// from LDS-resident W1 (+b1, relu, *dinv) -> h1h fp16 rows.
__global__ void gather_x_t1_kernel(const int4* __restrict__ hdr,
                                   const int* __restrict__ csr_src,
                                   const __half* __restrict__ xs,
                                   const float* __restrict__ W1,
                                   const float* __restrict__ b1,
                                   __half* __restrict__ h1h, int N) {
    __shared__ float W1s[12 * 64];    // 3 KB
    __shared__ float xrow[128][12];   // 6 KB
    const int tid = threadIdx.x;
    for (int u = tid; u < 12 * 64 / 4; u += 256)
        ((float4*)W1s)[u] = ((const float4*)W1)[u];

    const int t = blockIdx.x * 256 + tid;
    const bool valid = (t < N * 2);
    const int slot = t >> 1;
    const int c = t & 1;
    const int nl = tid >> 1;
    int4 H = valid ? hdr[slot] : make_int4(0, 0, 0, 0);
    const int* __restrict__ sp = csr_src + H.x;
    const int n = valid ? H.y : 0;
    const int i = H.z;
    const float di = __int_as_float(H.w);
    const int f0 = c * 8;

    float acc[8];
    {
        union { float4 f; __half2 h[4]; } u;
        u.f = *(const float4*)(xs + (size_t)i * 16 + f0);  // self loop
#pragma unroll
        for (int j = 0; j < 4; ++j) {
            float2 p = __half22float2(u.h[j]);
            acc[2 * j] = p.x; acc[2 * j + 1] = p.y;
        }
    }

    int k = 0;
    if (n >= 8) {
        int s[8];
#pragma unroll
        for (int j = 0; j < 8; ++j) s[j] = sp[j];
        for (; k + 16 <= n; k += 8) {
            int ns[8];
#pragma unroll
            for (int j = 0; j < 8; ++j) ns[j] = sp[k + 8 + j];
            float4 v[8];
#pragma unroll
            for (int j = 0; j < 8; ++j) v[j] = *(const float4*)(xs + (size_t)s[j] * 16 + f0);
#pragma unroll
            for (int j = 0; j < 8; ++j) h8_add(acc, v[j]);
#pragma unroll
            for (int j = 0; j < 8; ++j) s[j] = ns[j];
        }
        float4 v[8];
#pragma unroll
        for (int j = 0; j < 8; ++j) v[j] = *(const float4*)(xs + (size_t)s[j] * 16 + f0);
#pragma unroll
        for (int j = 0; j < 8; ++j) h8_add(acc, v[j]);
        k += 8;
    }
    for (; k + 4 <= n; k += 4) {
        int s0 = sp[k + 0], s1 = sp[k + 1], s2 = sp[k + 2], s3 = sp[k + 3];
        float4 v0 = *(const float4*)(xs + (size_t)s0 * 16 + f0);
        float4 v1 = *(const float4*)(xs + (size_t)s1 * 16 + f0);
        float4 v2 = *(const float4*)(xs + (size_t)s2 * 16 + f0);
        float4 v3 = *(const float4*)(xs + (size_t)s3 * 16 + f0);
        h8_add(acc, v0); h8_add(acc, v1); h8_add(acc, v2); h8_add(acc, v3);
    }
    for (; k < n; ++k) {
        float4 v = *(const float4*)(xs + (size_t)sp[k] * 16 + f0);
        h8_add(acc, v);
    }

    if (valid) {
        if (c == 0) {
#pragma unroll
            for (int j = 0; j < 8; ++j) xrow[nl][j] = acc[j] * di;
        } else {
#pragma unroll
            for (int j = 0; j < 4; ++j) xrow[nl][8 + j] = acc[j] * di;  // f 8..11
        }
    }
    __syncthreads();
    if (!valid) return;

    float xr[12];
#pragma unroll
    for (int j = 0; j < 12; ++j) xr[j] = xrow[nl][j];

    __half* op = h1h + (size_t)i * 64 + c * 32;
#pragma unroll
    for (int g = 0; g < 8; ++g) {
        const int c0 = c * 32 + g * 4;
        float4 r = *(const float4*)(b1 + c0);
#pragma unroll
        for (int kk = 0; kk < 12; ++kk) {
            const float4 w = *(const float4*)(W1s + kk * 64 + c0);
            r.x = fmaf(xr[kk], w.x, r.x);
            r.y = fmaf(xr[kk], w.y, r.y);
            r.z = fmaf(xr[kk], w.z, r.z);
            r.w = fmaf(xr[kk], w.w, r.w);
        }
        r.x = fmaxf(r.x, 0.f) * di; r.y = fmaxf(r.y, 0.f) * di;
        r.z = fmaxf(r.z, 0.f) * di; r.w = fmaxf(r.w, 0.f) * di;
        store_h4(op + g * 4, r);
    }
}

// ---------------- fused gather64 (block-coop) + MFMA layers 2+3 ----------------

// prep: W2 (64x128 f32, k-major) -> W2T (128x64 f16, n-major);
//       W3 (128x96 f32)          -> W3T (96x128 f16, n-major).
__global__ void prep_w_kernel(const float* __restrict__ W2, const float* __restrict__ W3,
                              __half* __restrict__ W2T, __half* __restrict__ W3T) {
    int i = blockIdx.x * 256 + threadIdx.x;
    if (i < 64 * 128) {
        int k = i >> 7, n = i & 127;
        W2T[n * 64 + k] = __float2half(W2[i]);
    } else {
        int j = i - 64 * 128;
        if (j < 128 * 96) {
            int k = j / 96, n = j - k * 96;
            W3T[n * 128 + k] = __float2half(W3[j]);
        }
    }
}

// Block handles 4 tiles (128 rows), 1 per wave.
// Phase 1 (block-wide): PROVEN gather64 loop (8 threads/node, 16B/edge, fp32
//   accum, unroll-8 prefetch) -> agg rows (fp16, *dinv) into LDS buf[p].
// Phase 2 (per wave, after 1 barrier): PROVEN t2/t3 MFMA path; A-frags read
//   from buf[wid]; h2 OVERLAYS the same region (a2 fully register-buffered
//   before overwrite; DS ops in-order per wave -> safe, no extra barrier).
// Frag layouts (gfx950, guide-verified):
//   A: lane holds A[row=l&31][k = kb*16 + (l>>5)*8 + j], j=0..7
//   B: lane holds B[k = kb*16 + (l>>5)*8 + j][col=l&31]  (n-major W^T rows)
//   C/D: elem r -> row = (r&3) + 8*(r>>2) + 4*(l>>5), col = l&31
// LB(256,2): 256-VGPR cap (spill-proof, as R16); LDS 34.8KB -> 4 blocks/CU.
__global__ void __launch_bounds__(256, 2)
fused_g64_t2t3_kernel(const __half* __restrict__ h1h,   // [N][64] f16 (pre-scaled rows)
                      const int* __restrict__ row_ptr, const int* __restrict__ deg,
                      const int* __restrict__ csr_src, const float* __restrict__ dinv,
                      const __half* __restrict__ W2T,   // [128][64] f16
                      const float* __restrict__ b2,     // [128]
                      const __half* __restrict__ W3T,   // [96][128] f16
                      __half* __restrict__ out,         // [N][96] f16
                      int N) {
    constexpr int LDH = 136;  // halves; 272B rows: 16B-aligned
    __shared__ _Float16 buf[4][32 * LDH];  // agg tiles, overlaid by h2 in phase 2
    const int tid = threadIdx.x;
    const int lane = tid & 63;
    const int wid = tid >> 6;
    const int l31 = lane & 31;
    const int lh = lane >> 5;  // 0/1
    const int NT = N >> 5;     // N % 32 == 0
    const int t0 = blockIdx.x * 4;

    // ---- phase 1: block-cooperative gather64 into LDS ----
    {
        const int nr = tid >> 3;        // node-row within tile (0..31)
        const int f0 = (tid & 7) * 8;   // feature start (halves)
#pragma unroll 1
        for (int p = 0; p < 4; ++p) {
            const int t = t0 + p;       // block-uniform
            if (t >= NT) break;
            const int i = (t << 5) + nr;
            const int* __restrict__ sp = csr_src + row_ptr[i];
            const int n = deg[i];
            const float di = dinv[i];

            float acc[8];
            {
                union { float4 f; __half2 h[4]; } u;
                u.f = *(const float4*)(h1h + (size_t)i * 64 + f0);  // self loop
#pragma unroll
                for (int j = 0; j < 4; ++j) {
                    float2 pp = __half22float2(u.h[j]);
                    acc[2 * j] = pp.x; acc[2 * j + 1] = pp.y;
                }
            }

            int k = 0;
            if (n >= 8) {
                int s[8];
#pragma unroll
                for (int j = 0; j < 8; ++j) s[j] = sp[j];
                for (; k + 16 <= n; k += 8) {
                    int ns[8];
#pragma unroll
                    for (int j = 0; j < 8; ++j) ns[j] = sp[k + 8 + j];
                    float4 v[8];
#pragma unroll
                    for (int j = 0; j < 8; ++j) v[j] = *(const float4*)(h1h + (size_t)s[j] * 64 + f0);
#pragma unroll
                    for (int j = 0; j < 8; ++j) h8_add(acc, v[j]);
#pragma unroll
                    for (int j = 0; j < 8; ++j) s[j] = ns[j];
                }
                float4 v[8];
#pragma unroll
                for (int j = 0; j < 8; ++j) v[j] = *(const float4*)(h1h + (size_t)s[j] * 64 + f0);
#pragma unroll
                for (int j = 0; j < 8; ++j) h8_add(acc, v[j]);
                k += 8;
            }
            for (; k + 4 <= n; k += 4) {
                int s0 = sp[k + 0], s1 = sp[k + 1], s2 = sp[k + 2], s3 = sp[k + 3];
                float4 v0 = *(const float4*)(h1h + (size_t)s0 * 64 + f0);
                float4 v1 = *(const float4*)(h1h + (size_t)s1 * 64 + f0);
                float4 v2 = *(const float4*)(h1h + (size_t)s2 * 64 + f0);
                float4 v3 = *(const float4*)(h1h + (size_t)s3 * 64 + f0);
                h8_add(acc, v0); h8_add(acc, v1); h8_add(acc, v2); h8_add(acc, v3);
            }
            for (; k < n; ++k) {
                float4 v = *(const float4*)(h1h + (size_t)sp[k] * 64 + f0);
                h8_add(acc, v);
            }

            union { float4 f; __half2 h[4]; } o;
            o.h[0] = __floats2half2_rn(acc[0] * di, acc[1] * di);
            o.h[1] = __floats2half2_rn(acc[2] * di, acc[3] * di);
            o.h[2] = __floats2half2_rn(acc[4] * di, acc[5] * di);
            o.h[3] = __floats2half2_rn(acc[6] * di, acc[7] * di);
            *(float4*)(&buf[p][nr * LDH + f0]) = o.f;
        }
    }
    __syncthreads();

    // ---- phase 2: per-wave t2/t3 MFMA on tile t0+wid ----
    const int t = t0 + wid;
    if (t >= NT) return;
    const int r0 = t << 5;
    _Float16* hs = buf[wid];

    float b2v[4];
#pragma unroll
    for (int nt = 0; nt < 4; ++nt) b2v[nt] = b2[nt * 32 + l31];

    // A-frags from LDS (agg rows), fully register-buffered before overwrite
    f16x8 a2[4];
#pragma unroll
    for (int kb = 0; kb < 4; ++kb)
        a2[kb] = *(const f16x8*)(hs + l31 * LDH + kb * 16 + lh * 8);

    // ---- t2 ----
#pragma unroll
    for (int nt = 0; nt < 4; ++nt) {
        f32x16 c = {0.f, 0.f, 0.f, 0.f, 0.f, 0.f, 0.f, 0.f,
                    0.f, 0.f, 0.f, 0.f, 0.f, 0.f, 0.f, 0.f};
#pragma unroll
        for (int kb = 0; kb < 4; ++kb) {
            f16x8 b = *(const f16x8*)(W2T + (size_t)(nt * 32 + l31) * 64 + kb * 16 + lh * 8);
            c = __builtin_amdgcn_mfma_f32_32x32x16_f16(a2[kb], b, c, 0, 0, 0);
        }
#pragma unroll
        for (int r = 0; r < 16; ++r) {
            int row = (r & 3) + 8 * (r >> 2) + 4 * lh;
            float v = fmaxf(c[r] + b2v[nt], 0.f);
            hs[row * LDH + nt * 32 + l31] = (_Float16)v;
        }
    }

    // ---- t3 ----
    f16x8 a3[8];
#pragma unroll
    for (int kb = 0; kb < 8; ++kb)
        a3[kb] = *(const f16x8*)(hs + l31 * LDH + kb * 16 + lh * 8);
    float4 dv[4];
#pragma unroll
    for (int rg = 0; rg < 4; ++rg)
        dv[rg] = *(const float4*)(dinv + r0 + rg * 8 + lh * 4);
#pragma unroll
    for (int nt = 0; nt < 3; ++nt) {
        f32x16 c = {0.f, 0.f, 0.f, 0.f, 0.f, 0.f, 0.f, 0.f,
                    0.f, 0.f, 0.f, 0.f, 0.f, 0.f, 0.f, 0.f};
#pragma unroll
        for (int kb = 0; kb < 8; ++kb) {
            f16x8 b = *(const f16x8*)(W3T + (size_t)(nt * 32 + l31) * 128 + kb * 16 + lh * 8);
            c = __builtin_amdgcn_mfma_f32_32x32x16_f16(a3[kb], b, c, 0, 0, 0);
        }
#pragma unroll
        for (int r = 0; r < 16; ++r) {
            int row = (r & 3) + 8 * (r >> 2) + 4 * lh;
            float dvv = ((const float*)&dv[r >> 2])[r & 3];
            hs[row * LDH + nt * 32 + l31] = (_Float16)(c[r] * dvv);
        }
    }

    // ---- coalesced out-tile store: 32 rows x 192B = 6KB contiguous ----
#pragma unroll
    for (int it = 0; it < 6; ++it) {
        int id = lane + it * 64;       // 384 16B-chunks
        int row = id / 12, ch = id - row * 12;
        float4 v = *(const float4*)(hs + row * LDH + ch * 8);
        *(float4*)((char*)(out + (size_t)r0 * 96) + (size_t)id * 16) = v;
    }
}

// ---------------- pull gather (unroll-8, index-prefetched, hdr-packed) ----------------

// fp16-input gather: 8 features/thread (16 B/edge), fp32 accum, LPT order via hdr.
template <int F, bool HAS_BIAS, bool OUT_HALF>
__global__ void gather_h_kernel(const int4* __restrict__ hdr, const int* __restrict__ csr_src,
                                const __half* __restrict__ hws,
                                const float* __restrict__ b, void* __restrict__ out_v, int N) {
    constexpr int TPN = F / 8;
    int t = blockIdx.x * blockDim.x + threadIdx.x;
    if (t >= N * TPN) return;
    int slot = t / TPN;
    int c = t - slot * TPN;
    const int4 H = hdr[slot];
    const int* __restrict__ sp = csr_src + H.x;
    const int n = H.y;
    const int i = H.z;
    const float di = __int_as_float(H.w);
    int f0 = c * 8;

    float acc[8];
    {
        union { float4 f; __half2 h[4]; } u;
        u.f = *(const float4*)(hws + (size_t)i * F + f0);  // self loop
#pragma unroll
        for (int j = 0; j < 4; ++j) {
            float2 p = __half22float2(u.h[j]);
            acc[2 * j] = p.x; acc[2 * j + 1] = p.y;
        }
    }

    int k = 0;
    if (n >= 8) {
        int s[8];
#pragma unroll
        for (int j = 0; j < 8; ++j) s[j] = sp[j];
        for (; k + 16 <= n; k += 8) {
            int ns[8];
#pragma unroll
            for (int j = 0; j < 8; ++j) ns[j] = sp[k + 8 + j];
            float4 v[8];
#pragma unroll
            for (int j = 0; j < 8; ++j) v[j] = *(const float4*)(hws + (size_t)s[j] * F + f0);
#pragma unroll
            for (int j = 0; j < 8; ++j) h8_add(acc, v[j]);
#pragma unroll
            for (int j = 0; j < 8; ++j) s[j] = ns[j];
        }
        float4 v[8];
#pragma unroll
        for (int j = 0; j < 8; ++j) v[j] = *(const float4*)(hws + (size_t)s[j] * F + f0);
#pragma unroll
        for (int j = 0; j < 8; ++j) h8_add(acc, v[j]);
        k += 8;
    }
    for (; k + 4 <= n; k += 4) {
        int s0 = sp[k + 0], s1 = sp[k + 1], s2 = sp[k + 2], s3 = sp[k + 3];
        float4 v0 = *(const float4*)(hws + (size_t)s0 * F + f0);
        float4 v1 = *(const float4*)(hws + (size_t)s1 * F + f0);
        float4 v2 = *(const float4*)(hws + (size_t)s2 * F + f0);
        float4 v3 = *(const float4*)(hws + (size_t)s3 * F + f0);
        h8_add(acc, v0); h8_add(acc, v1); h8_add(acc, v2); h8_add(acc, v3);
    }
    for (; k < n; ++k) {
        float4 v = *(const float4*)(hws + (size_t)sp[k] * F + f0);
        h8_add(acc, v);
    }

    float4 r0, r1;
    if (HAS_BIAS) {
        const float4 bb0 = *(const float4*)(b + f0);
        const float4 bb1 = *(const float4*)(b + f0 + 4);
        r0.x = fmaf(acc[0], di, bb0.x); r0.y = fmaf(acc[1], di, bb0.y);
        r0.z = fmaf(acc[2], di, bb0.z); r0.w = fmaf(acc[3], di, bb0.w);
        r1.x = fmaf(acc[4], di, bb1.x); r1.y = fmaf(acc[5], di, bb1.y);
        r1.z = fmaf(acc[6], di, bb1.z); r1.w = fmaf(acc[7], di, bb1.w);
    } else {
        r0.x = acc[0] * di; r0.y = acc[1] * di; r0.z = acc[2] * di; r0.w = acc[3] * di;
        r1.x = acc[4] * di; r1.y = acc[5] * di; r1.z = acc[6] * di; r1.w = acc[7] * di;
    }
    if (OUT_HALF) {
        union { float4 f; __half2 h[4]; } u;
        u.h[0] = __floats2half2_rn(r0.x, r0.y);
        u.h[1] = __floats2half2_rn(r0.z, r0.w);
        u.h[2] = __floats2half2_rn(r1.x, r1.y);
        u.h[3] = __floats2half2_rn(r1.z, r1.w);
        nt_store_raw16((__half*)out_v + (size_t)i * F + f0, u.f);
    } else {
        float* op = (float*)out_v + (size_t)i * F + f0;
        nt_store_raw16(op, r0);
        nt_store_raw16(op + 4, r1);
    }
}

// ---------------- launch ----------------

extern "C" void kernel_launch(void* const* d_in, const int* in_sizes, int n_in,
                              void* d_out, int out_size, void* d_ws, size_t ws_size,
                              hipStream_t stream) {
    const float* x  = (const float*)d_in[0];
    const int*   ei = (const int*)d_in[1];  // (2,E): row0=src, row1=dst
    const float* W1 = (const float*)d_in[2];
    const float* b1 = (const float*)d_in[3];
    const float* W2 = (const float*)d_in[4];
    const float* b2 = (const float*)d_in[5];
    const float* W3 = (const float*)d_in[6];
    const float* b3 = (const float*)d_in[7];
    float* out = (float*)d_out;

    const int N = in_sizes[0] / 12;
    const int E = in_sizes[1] / 2;
    const int NB = cdiv(N, BNODES);  // 196 dst buckets (<=256)

    // workspace layout
    char* ws = (char*)d_ws;
    int*   deg     = (int*)ws;    ws += (size_t)N * sizeof(int);
    int*   row_ptr = (int*)ws;    ws += (size_t)N * sizeof(int);
    int*   bcnt    = (int*)ws;    ws += 256 * sizeof(int);
    int*   dh      = (int*)ws;    ws += 64 * sizeof(int);
    int*   dcur    = (int*)ws;    ws += 64 * sizeof(int);
    int*   gcur    = (int*)ws;    ws += 256 * sizeof(int);
    float* dinv    = (float*)ws;  ws += (size_t)N * sizeof(float);
    int4*  hdr     = (int4*)ws;   ws += (size_t)N * sizeof(int4);
    __half* W2Th   = (__half*)ws; ws += 128 * 64 * sizeof(__half);
    __half* W3Th   = (__half*)ws; ws += 96 * 128 * sizeof(__half);
    int*   csr_src = (int*)ws;    ws += (size_t)E * sizeof(int);
    float* bufA    = (float*)ws;  ws += (size_t)N * 128 * sizeof(float);  // xs / hw3h
    float* bufB    = (float*)ws;                                          // binned / h1h
    unsigned* binned = (unsigned*)bufB;  // aliased: consumed before bufB reused

    // ---- CSR build (fully bucketed) + weight prep ----
    // zero bcnt + dh + dcur + gcur (contiguous: 256+64+64+256 ints)
    hipMemsetAsync(bcnt, 0, (256 + 64 + 64 + 256) * sizeof(int), stream);
    prep_w_kernel<<<80, 256, 0, stream>>>(W2, W3, W2Th, W3Th);
    bucket_count_kernel<8192><<<cdiv(E, 8192), BLOCK, 0, stream>>>(ei + E, E, bcnt, NB);
    bin_edges_kernel<8192><<<cdiv(E, 8192), BLOCK, 0, stream>>>(ei, E, bcnt, gcur, binned, NB);
    csr_fill_kernel<<<NB, 1024, 0, stream>>>(bcnt, binned, deg, dinv, row_ptr,
                                             csr_src, dh, N);

    // ---- degree counting sort -> packed headers (scan folded in) ----
    dperm_kernel<<<cdiv(N, BLOCK), BLOCK, 0, stream>>>(deg, row_ptr, dinv, dh, dcur, hdr, N);

    // ---- layer 1: prescale->fp16, fused aggregate@F=16h + 12->64 transform ----
    prescale_h_kernel<<<cdiv(N, BLOCK), BLOCK, 0, stream>>>(x, dinv, (__half*)bufA, N);
    gather_x_t1_kernel<<<cdiv(N * 2, BLOCK), BLOCK, 0, stream>>>(
        hdr, csr_src, (const __half*)bufA, W1, b1, (__half*)bufB, N);  // bufB = h1h

    // ---- layers 2+3: block-coop gather@F=64 + relu(.@W2+b2)@W3*dinv, ONE kernel ----
    fused_g64_t2t3_kernel<<<cdiv(N / 32, 4), 256, 0, stream>>>(
        (const __half*)bufB, row_ptr, deg, csr_src, dinv, W2Th, b2, W3Th,
        (__half*)bufA, N);  // bufA = hw3h

    // ---- layer 3 aggregate at F=96 (+b3) -> out ----
    gather_h_kernel<96, true, false><<<cdiv(N * 12, BLOCK), BLOCK, 0, stream>>>(
        hdr, csr_src, (const __half*)bufA, b3, out, N);
}

// Round 12
// 264.687 us; speedup vs baseline: 2.3824x; 1.0333x over previous
//
#include <hip/hip_runtime.h>
#include <hip/hip_bf16.h>
#include <hip/hip_fp16.h>

// GCN 3-layer: x(N,12) -> 64 -> 128 -> 96, symmetric normalization + self loops.
// N=100000, E=1600000.
//
// R2: CSR + pull-gather (7028 -> 1364 us).           R3: 4x4-tile transform (-> 693).
// R4: aggregate at min-width 12/64/96, prescale (-> 550).
// R5/R6/R8: bucketed CSR build, nt stores, degree sort (-> 444).
// R9: fp16 feature rows for gathers (-> 382).
// R10: v_dot2_f32_f16 transforms + packed edge binning (-> 352).
// R11: layers 2+3 fused into ONE MFMA kernel; LPT gather order (-> 328).
// R13/R14: csr_fill@1024, packed hdr (-> 324).
// R16: __launch_bounds__(256,2) on fused killed a 150MB accumulator spill (-> 289).
// R17: per-lane register gather fused into MFMA: REGRESSED (scratch + lost MLP).
// R18: block-cooperative g64+MFMA fusion (-> 276).
// R19/R20: XCD slice-pinning: REGRESSED both ways. Random-gather service
//      (~3.8 TB/s miss path) is a structural floor. Abandoned.
// R21: scan kernels folded into consumers (-> 273.5).
// R22: (a) bucket_count DELETED: slotted binning (binned[b*SLOT+..], bcnt is
//      both cursor and total; SLOT=16384 = mean+91sigma for uniform dst).
//      Saves a full 6.4MB pass + launch. (b) prescale folded into dperm
//      (dinv[i] already in register there). Launches 10 -> 8.

static inline int cdiv(int a, int b) { return (a + b - 1) / b; }
constexpr int BLOCK = 256;
constexpr int BSHIFT = 9;                  // 512 nodes per bucket
constexpr int BNODES = 1 << BSHIFT;
constexpr int SLOT = 16384;                // binned slot per bucket (mean 8192)

typedef float nfloat4 __attribute__((ext_vector_type(4)));
typedef _Float16 f16x8 __attribute__((ext_vector_type(8)));
typedef float f32x16 __attribute__((ext_vector_type(16)));

// ---------------- small utils ----------------

__device__ __forceinline__ void nt_store_raw16(void* p, float4 v) {
    nfloat4 nv;
    nv.x = v.x; nv.y = v.y; nv.z = v.z; nv.w = v.w;
    __builtin_nontemporal_store(nv, (nfloat4*)p);
}

struct h4 { __half2 a, b; };  // 8 bytes = 4 fp16
__device__ __forceinline__ void store_h4(__half* p, float4 v) {
    h4 r;
    r.a = __floats2half2_rn(v.x, v.y);
    r.b = __floats2half2_rn(v.z, v.w);
    *(h4*)p = r;
}

// unpack 8 fp16 (one float4 raw load) and add into acc[0..7]
__device__ __forceinline__ void h8_add(float* acc, float4 raw) {
    union { float4 f; __half2 h[4]; } u;
    u.f = raw;
#pragma unroll
    for (int j = 0; j < 4; ++j) {
        float2 p = __half22float2(u.h[j]);
        acc[2 * j] += p.x;
        acc[2 * j + 1] += p.y;
    }
}

// ---------------- CSR build (slotted, bucket_count-free) ----------------

// Bin edges by dst bucket into slotted regions binned[b*SLOT .. ]; bcnt[b] is
// simultaneously the append cursor and (after completion) the bucket total.
// Entry packed as s | (dst_local << 17).
template <int CHUNK>
__global__ void bin_edges_kernel(const int* __restrict__ ei, int E,
                                 int* __restrict__ bcnt, unsigned* __restrict__ binned,
                                 int NB) {
    __shared__ int cnt[256], base[256], rk[256];
    const int t = threadIdx.x;
    for (int i = t; i < NB; i += blockDim.x) { cnt[i] = 0; rk[i] = 0; }
    __syncthreads();
    const int e0 = blockIdx.x * CHUNK;
    const int e1 = min(e0 + CHUNK, E);
    for (int e = e0 + t; e < e1; e += blockDim.x)
        atomicAdd(&cnt[ei[E + e] >> BSHIFT], 1);
    __syncthreads();
    for (int i = t; i < NB; i += blockDim.x)
        base[i] = i * SLOT + (cnt[i] ? atomicAdd(&bcnt[i], cnt[i]) : 0);
    __syncthreads();
    for (int e = e0 + t; e < e1; e += blockDim.x) {
        int s = ei[e], d = ei[E + e];
        int b = d >> BSHIFT;
        int r = atomicAdd(&rk[b], 1);
        binned[base[b] + r] = (unsigned)s | ((unsigned)(d & (BNODES - 1)) << 17);
    }
}

// Phase B: one block per bucket, 1024 threads. Reads its slot; LDS degree hist
// + pair-scan -> deg/dinv/row_ptr; csr_src base via local scan of bcnt;
// 64-bin degree hist folded in.
__global__ void csr_fill_kernel(const int* __restrict__ bcnt,
                                const unsigned* __restrict__ binned,
                                int* __restrict__ deg, float* __restrict__ dinv,
                                int* __restrict__ row_ptr, int* __restrict__ csr_src,
                                int* __restrict__ dh, int N) {
    __shared__ int c[BNODES];    // counts, then cursors
    __shared__ int ps[256];      // scans
    __shared__ int dhloc[64];
    __shared__ int sbase;
    const int t = threadIdx.x;   // 0..1023
    const int b = blockIdx.x;
    const int node0 = b << BSHIFT;
    if (t < BNODES) c[t] = 0;
    if (t < 64) dhloc[t] = 0;
    if (t < 256) ps[t] = bcnt[t];
    __syncthreads();
    for (int off = 1; off < 256; off <<= 1) {
        int add = (t >= off && t < 256) ? ps[t - off] : 0;
        __syncthreads();
        if (t < 256) ps[t] += add;
        __syncthreads();
    }
    if (t == 0) sbase = (b == 0) ? 0 : ps[b - 1];
    __syncthreads();
    const int base = sbase;            // csr_src base for this bucket
    const int cb = bcnt[b];            // bucket edge count
    const unsigned* __restrict__ bin = binned + (size_t)b * SLOT;
    for (int e = t; e < cb; e += 1024)
        atomicAdd(&c[bin[e] >> 17], 1);
    __syncthreads();
    int s0 = 0, s1 = 0;
    if (t < 256) {
        s0 = c[2 * t]; s1 = c[2 * t + 1];
        ps[t] = s0 + s1;
    }
    __syncthreads();
    for (int off = 1; off < 256; off <<= 1) {
        int add = (t >= off && t < 256) ? ps[t - off] : 0;
        __syncthreads();
        if (t < 256) ps[t] += add;
        __syncthreads();
    }
    if (t < 256) {
        const int ex = ps[t] - (s0 + s1);
        const int p0 = base + ex;
        const int p1 = p0 + s0;
        const int n0 = node0 + 2 * t;
        if (n0 < N) {
            row_ptr[n0] = p0; deg[n0] = s0; dinv[n0] = rsqrtf((float)s0 + 1.0f);
            atomicAdd(&dhloc[min(s0, 63)], 1);
            if (n0 + 1 < N) {
                row_ptr[n0 + 1] = p1; deg[n0 + 1] = s1; dinv[n0 + 1] = rsqrtf((float)s1 + 1.0f);
                atomicAdd(&dhloc[min(s1, 63)], 1);
            }
        }
        c[2 * t] = p0; c[2 * t + 1] = p1;
    }
    __syncthreads();
    if (t < 64 && dhloc[t]) atomicAdd(&dh[t], dhloc[t]);
    for (int e = t; e < cb; e += 1024) {
        unsigned sd = bin[e];
        int pos = atomicAdd(&c[sd >> 17], 1);
        csr_src[pos] = (int)(sd & 0x1FFFFu);
    }
}

// ---------------- degree counting sort -> packed headers (+ prescale) ----------------

// Each block computes the 64-bin exclusive scan of dh locally; zero-init
// cursor dcur gives cross-block ranks. hdr[N-1-slot] = {row_ptr, deg, node,
// dinv_bits}: slot 0 = highest degree (LPT). R22: prescale folded in —
// xs[i] = fp16(x[i] * dinv[i]) padded to 16 halves.
__global__ void dperm_kernel(const int* __restrict__ deg, const int* __restrict__ row_ptr,
                             const float* __restrict__ dinv, const int* __restrict__ dh,
                             int* __restrict__ dcur, int4* __restrict__ hdr,
                             const float* __restrict__ x, __half* __restrict__ xs, int N) {
    __shared__ int cnt[64], base[64], rk[64], sc[64];
    const int t = threadIdx.x;
    if (t < 64) {
        cnt[t] = 0; rk[t] = 0;
        sc[t] = dh[t];
    }
    __syncthreads();
    for (int off = 1; off < 64; off <<= 1) {
        int add = (t >= off && t < 64) ? sc[t - off] : 0;
        __syncthreads();
        if (t < 64) sc[t] += add;
        __syncthreads();
    }
    const int i = blockIdx.x * blockDim.x + t;
    const int d = (i < N) ? deg[i] : 0;
    const int myb = (i < N) ? min(d, 63) : -1;
    const float di = (i < N) ? dinv[i] : 0.f;
    if (myb >= 0) atomicAdd(&cnt[myb], 1);
    __syncthreads();
    if (t < 64) {
        const int ex = sc[t] - dh[t];
        base[t] = ex + (cnt[t] ? atomicAdd(&dcur[t], cnt[t]) : 0);
    }
    __syncthreads();
    if (myb >= 0) {
        int r = atomicAdd(&rk[myb], 1);
        int slot = base[myb] + r;
        int4 h;
        h.x = row_ptr[i];
        h.y = d;
        h.z = i;
        h.w = __float_as_int(di);
        hdr[N - 1 - slot] = h;

        // ---- prescale (folded): xs[i][0..15] = fp16(x[i][0..11]*di), pad 0 ----
        const float4* xr = (const float4*)(x + (size_t)i * 12);
        float4 a = xr[0], b = xr[1], c = xr[2];
        union { float4 f; __half2 h2[4]; } u0, u1;
        u0.h2[0] = __floats2half2_rn(a.x * di, a.y * di);
        u0.h2[1] = __floats2half2_rn(a.z * di, a.w * di);
        u0.h2[2] = __floats2half2_rn(b.x * di, b.y * di);
        u0.h2[3] = __floats2half2_rn(b.z * di, b.w * di);
        u1.h2[0] = __floats2half2_rn(c.x * di, c.y * di);
        u1.h2[1] = __floats2half2_rn(c.z * di, c.w * di);
        u1.h2[2] = __floats2half2_rn(0.f, 0.f);
        u1.h2[3] = __floats2half2_rn(0.f, 0.f);
        float4* op = (float4*)(xs + (size_t)i * 16);
        op[0] = u0.f;
        op[1] = u1.f;
    }
}

// ---------------- fused gather_x + transform-1 ----------------

// Phase 1: aggregate xs (fp16 [N][16], prescaled) at F=16h, 2 threads/node,
// results (scaled by dinv) into LDS xrow[128][12].  Phase 2: 12->64 transform
// from LDS-resident W1 (+b1, relu, *dinv) -> h1h fp16 rows.
__global__ void gather_x_t1_kernel(const int4* __restrict__ hdr,
                                   const int* __restrict__ csr_src,
                                   const __half* __restrict__ xs,
                                   const float* __restrict__ W1,
                                   const float* __restrict__ b1,
                                   __half* __restrict__ h1h, int N) {
    __shared__ float W1s[12 * 64];    // 3 KB
    __shared__ float xrow[128][12];   // 6 KB
    const int tid = threadIdx.x;
    for (int u = tid; u < 12 * 64 / 4; u += 256)
        ((float4*)W1s)[u] = ((const float4*)W1)[u];

    const int t = blockIdx.x * 256 + tid;
    const bool valid = (t < N * 2);
    const int slot = t >> 1;
    const int c = t & 1;
    const int nl = tid >> 1;
    int4 H = valid ? hdr[slot] : make_int4(0, 0, 0, 0);
    const int* __restrict__ sp = csr_src + H.x;
    const int n = valid ? H.y : 0;
    const int i = H.z;
    const float di = __int_as_float(H.w);
    const int f0 = c * 8;

    float acc[8];
    {
        union { float4 f; __half2 h[4]; } u;
        u.f = *(const float4*)(xs + (size_t)i * 16 + f0);  // self loop
#pragma unroll
        for (int j = 0; j < 4; ++j) {
            float2 p = __half22float2(u.h[j]);
            acc[2 * j] = p.x; acc[2 * j + 1] = p.y;
        }
    }

    int k = 0;
    if (n >= 8) {
        int s[8];
#pragma unroll
        for (int j = 0; j < 8; ++j) s[j] = sp[j];
        for (; k + 16 <= n; k += 8) {
            int ns[8];
#pragma unroll
            for (int j = 0; j < 8; ++j) ns[j] = sp[k + 8 + j];
            float4 v[8];
#pragma unroll
            for (int j = 0; j < 8; ++j) v[j] = *(const float4*)(xs + (size_t)s[j] * 16 + f0);
#pragma unroll
            for (int j = 0; j < 8; ++j) h8_add(acc, v[j]);
#pragma unroll
            for (int j = 0; j < 8; ++j) s[j] = ns[j];
        }
        float4 v[8];
#pragma unroll
        for (int j = 0; j < 8; ++j) v[j] = *(const float4*)(xs + (size_t)s[j] * 16 + f0);
#pragma unroll
        for (int j = 0; j < 8; ++j) h8_add(acc, v[j]);
        k += 8;
    }
    for (; k + 4 <= n; k += 4) {
        int s0 = sp[k + 0], s1 = sp[k + 1], s2 = sp[k + 2], s3 = sp[k + 3];
        float4 v0 = *(const float4*)(xs + (size_t)s0 * 16 + f0);
        float4 v1 = *(const float4*)(xs + (size_t)s1 * 16 + f0);
        float4 v2 = *(const float4*)(xs + (size_t)s2 * 16 + f0);
        float4 v3 = *(const float4*)(xs + (size_t)s3 * 16 + f0);
        h8_add(acc, v0); h8_add(acc, v1); h8_add(acc, v2); h8_add(acc, v3);
    }
    for (; k < n; ++k) {
        float4 v = *(const float4*)(xs + (size_t)sp[k] * 16 + f0);
        h8_add(acc, v);
    }

    if (valid) {
        if (c == 0) {
#pragma unroll
            for (int j = 0; j < 8; ++j) xrow[nl][j] = acc[j] * di;
        } else {
#pragma unroll
            for (int j = 0; j < 4; ++j) xrow[nl][8 + j] = acc[j] * di;  // f 8..11
        }
    }
    __syncthreads();
    if (!valid) return;

    float xr[12];
#pragma unroll
    for (int j = 0; j < 12; ++j) xr[j] = xrow[nl][j];

    __half* op = h1h + (size_t)i * 64 + c * 32;
#pragma unroll
    for (int g = 0; g < 8; ++g) {
        const int c0 = c * 32 + g * 4;
        float4 r = *(const float4*)(b1 + c0);
#pragma unroll
        for (int kk = 0; kk < 12; ++kk) {
            const float4 w = *(const float4*)(W1s + kk * 64 + c0);
            r.x = fmaf(xr[kk], w.x, r.x);
            r.y = fmaf(xr[kk], w.y, r.y);
            r.z = fmaf(xr[kk], w.z, r.z);
            r.w = fmaf(xr[kk], w.w, r.w);
        }
        r.x = fmaxf(r.x, 0.f) * di; r.y = fmaxf(r.y, 0.f) * di;
        r.z = fmaxf(r.z, 0.f) * di; r.w = fmaxf(r.w, 0.f) * di;
        store_h4(op + g * 4, r);
    }
}

// ---------------- fused gather64 (block-coop) + MFMA layers 2+3 ----------------

// prep: W2 (64x128 f32, k-major) -> W2T (128x64 f16, n-major);
//       W3 (128x96 f32)          -> W3T (96x128 f16, n-major).
__global__ void prep_w_kernel(const float* __restrict__ W2, const float* __restrict__ W3,
                              __half* __restrict__ W2T, __half* __restrict__ W3T) {
    int i = blockIdx.x * 256 + threadIdx.x;
    if (i < 64 * 128) {
        int k = i >> 7, n = i & 127;
        W2T[n * 64 + k] = __float2half(W2[i]);
    } else {
        int j = i - 64 * 128;
        if (j < 128 * 96) {
            int k = j / 96, n = j - k * 96;
            W3T[n * 128 + k] = __float2half(W3[j]);
        }
    }
}

// Block handles 4 tiles (128 rows), 1 per wave.
// Phase 1 (block-wide): PROVEN gather64 loop (8 threads/node, 16B/edge, fp32
//   accum, unroll-8 prefetch) -> agg rows (fp16, *dinv) into LDS buf[p].
// Phase 2 (per wave, after 1 barrier): PROVEN t2/t3 MFMA path; A-frags read
//   from buf[wid]; h2 OVERLAYS the same region (a2 fully register-buffered
//   before overwrite; DS ops in-order per wave -> safe, no extra barrier).
// Frag layouts (gfx950, guide-verified):
//   A: lane holds A[row=l&31][k = kb*16 + (l>>5)*8 + j], j=0..7
//   B: lane holds B[k = kb*16 + (l>>5)*8 + j][col=l&31]  (n-major W^T rows)
//   C/D: elem r -> row = (r&3) + 8*(r>>2) + 4*(l>>5), col = l&31
// LB(256,2): 256-VGPR cap (spill-proof, as R16); LDS 34.8KB -> 4 blocks/CU.
__global__ void __launch_bounds__(256, 2)
fused_g64_t2t3_kernel(const __half* __restrict__ h1h,   // [N][64] f16 (pre-scaled rows)
                      const int* __restrict__ row_ptr, const int* __restrict__ deg,
                      const int* __restrict__ csr_src, const float* __restrict__ dinv,
                      const __half* __restrict__ W2T,   // [128][64] f16
                      const float* __restrict__ b2,     // [128]
                      const __half* __restrict__ W3T,   // [96][128] f16
                      __half* __restrict__ out,         // [N][96] f16
                      int N) {
    constexpr int LDH = 136;  // halves; 272B rows: 16B-aligned
    __shared__ _Float16 buf[4][32 * LDH];  // agg tiles, overlaid by h2 in phase 2
    const int tid = threadIdx.x;
    const int lane = tid & 63;
    const int wid = tid >> 6;
    const int l31 = lane & 31;
    const int lh = lane >> 5;  // 0/1
    const int NT = N >> 5;     // N % 32 == 0
    const int t0 = blockIdx.x * 4;

    // ---- phase 1: block-cooperative gather64 into LDS ----
    {
        const int nr = tid >> 3;        // node-row within tile (0..31)
        const int f0 = (tid & 7) * 8;   // feature start (halves)
#pragma unroll 1
        for (int p = 0; p < 4; ++p) {
            const int t = t0 + p;       // block-uniform
            if (t >= NT) break;
            const int i = (t << 5) + nr;
            const int* __restrict__ sp = csr_src + row_ptr[i];
            const int n = deg[i];
            const float di = dinv[i];

            float acc[8];
            {
                union { float4 f; __half2 h[4]; } u;
                u.f = *(const float4*)(h1h + (size_t)i * 64 + f0);  // self loop
#pragma unroll
                for (int j = 0; j < 4; ++j) {
                    float2 pp = __half22float2(u.h[j]);
                    acc[2 * j] = pp.x; acc[2 * j + 1] = pp.y;
                }
            }

            int k = 0;
            if (n >= 8) {
                int s[8];
#pragma unroll
                for (int j = 0; j < 8; ++j) s[j] = sp[j];
                for (; k + 16 <= n; k += 8) {
                    int ns[8];
#pragma unroll
                    for (int j = 0; j < 8; ++j) ns[j] = sp[k + 8 + j];
                    float4 v[8];
#pragma unroll
                    for (int j = 0; j < 8; ++j) v[j] = *(const float4*)(h1h + (size_t)s[j] * 64 + f0);
#pragma unroll
                    for (int j = 0; j < 8; ++j) h8_add(acc, v[j]);
#pragma unroll
                    for (int j = 0; j < 8; ++j) s[j] = ns[j];
                }
                float4 v[8];
#pragma unroll
                for (int j = 0; j < 8; ++j) v[j] = *(const float4*)(h1h + (size_t)s[j] * 64 + f0);
#pragma unroll
                for (int j = 0; j < 8; ++j) h8_add(acc, v[j]);
                k += 8;
            }
            for (; k + 4 <= n; k += 4) {
                int s0 = sp[k + 0], s1 = sp[k + 1], s2 = sp[k + 2], s3 = sp[k + 3];
                float4 v0 = *(const float4*)(h1h + (size_t)s0 * 64 + f0);
                float4 v1 = *(const float4*)(h1h + (size_t)s1 * 64 + f0);
                float4 v2 = *(const float4*)(h1h + (size_t)s2 * 64 + f0);
                float4 v3 = *(const float4*)(h1h + (size_t)s3 * 64 + f0);
                h8_add(acc, v0); h8_add(acc, v1); h8_add(acc, v2); h8_add(acc, v3);
            }
            for (; k < n; ++k) {
                float4 v = *(const float4*)(h1h + (size_t)sp[k] * 64 + f0);
                h8_add(acc, v);
            }

            union { float4 f; __half2 h[4]; } o;
            o.h[0] = __floats2half2_rn(acc[0] * di, acc[1] * di);
            o.h[1] = __floats2half2_rn(acc[2] * di, acc[3] * di);
            o.h[2] = __floats2half2_rn(acc[4] * di, acc[5] * di);
            o.h[3] = __floats2half2_rn(acc[6] * di, acc[7] * di);
            *(float4*)(&buf[p][nr * LDH + f0]) = o.f;
        }
    }
    __syncthreads();

    // ---- phase 2: per-wave t2/t3 MFMA on tile t0+wid ----
    const int t = t0 + wid;
    if (t >= NT) return;
    const int r0 = t << 5;
    _Float16* hs = buf[wid];

    float b2v[4];
#pragma unroll
    for (int nt = 0; nt < 4; ++nt) b2v[nt] = b2[nt * 32 + l31];

    // A-frags from LDS (agg rows), fully register-buffered before overwrite
    f16x8 a2[4];
#pragma unroll
    for (int kb = 0; kb < 4; ++kb)
        a2[kb] = *(const f16x8*)(hs + l31 * LDH + kb * 16 + lh * 8);

    // ---- t2 ----
#pragma unroll
    for (int nt = 0; nt < 4; ++nt) {
        f32x16 c = {0.f, 0.f, 0.f, 0.f, 0.f, 0.f, 0.f, 0.f,
                    0.f, 0.f, 0.f, 0.f, 0.f, 0.f, 0.f, 0.f};
#pragma unroll
        for (int kb = 0; kb < 4; ++kb) {
            f16x8 b = *(const f16x8*)(W2T + (size_t)(nt * 32 + l31) * 64 + kb * 16 + lh * 8);
            c = __builtin_amdgcn_mfma_f32_32x32x16_f16(a2[kb], b, c, 0, 0, 0);
        }
#pragma unroll
        for (int r = 0; r < 16; ++r) {
            int row = (r & 3) + 8 * (r >> 2) + 4 * lh;
            float v = fmaxf(c[r] + b2v[nt], 0.f);
            hs[row * LDH + nt * 32 + l31] = (_Float16)v;
        }
    }

    // ---- t3 ----
    f16x8 a3[8];
#pragma unroll
    for (int kb = 0; kb < 8; ++kb)
        a3[kb] = *(const f16x8*)(hs + l31 * LDH + kb * 16 + lh * 8);
    float4 dv[4];
#pragma unroll
    for (int rg = 0; rg < 4; ++rg)
        dv[rg] = *(const float4*)(dinv + r0 + rg * 8 + lh * 4);
#pragma unroll
    for (int nt = 0; nt < 3; ++nt) {
        f32x16 c = {0.f, 0.f, 0.f, 0.f, 0.f, 0.f, 0.f, 0.f,
                    0.f, 0.f, 0.f, 0.f, 0.f, 0.f, 0.f, 0.f};
#pragma unroll
        for (int kb = 0; kb < 8; ++kb) {
            f16x8 b = *(const f16x8*)(W3T + (size_t)(nt * 32 + l31) * 128 + kb * 16 + lh * 8);
            c = __builtin_amdgcn_mfma_f32_32x32x16_f16(a3[kb], b, c, 0, 0, 0);
        }
#pragma unroll
        for (int r = 0; r < 16; ++r) {
            int row = (r & 3) + 8 * (r >> 2) + 4 * lh;
            float dvv = ((const float*)&dv[r >> 2])[r & 3];
            hs[row * LDH + nt * 32 + l31] = (_Float16)(c[r] * dvv);
        }
    }

    // ---- coalesced out-tile store: 32 rows x 192B = 6KB contiguous ----
#pragma unroll
    for (int it = 0; it < 6; ++it) {
        int id = lane + it * 64;       // 384 16B-chunks
        int row = id / 12, ch = id - row * 12;
        float4 v = *(const float4*)(hs + row * LDH + ch * 8);
        *(float4*)((char*)(out + (size_t)r0 * 96) + (size_t)id * 16) = v;
    }
}

// ---------------- pull gather (unroll-8, index-prefetched, hdr-packed) ----------------

// fp16-input gather: 8 features/thread (16 B/edge), fp32 accum, LPT order via hdr.
template <int F, bool HAS_BIAS, bool OUT_HALF>
__global__ void gather_h_kernel(const int4* __restrict__ hdr, const int* __restrict__ csr_src,
                                const __half* __restrict__ hws,
                                const float* __restrict__ b, void* __restrict__ out_v, int N) {
    constexpr int TPN = F / 8;
    int t = blockIdx.x * blockDim.x + threadIdx.x;
    if (t >= N * TPN) return;
    int slot = t / TPN;
    int c = t - slot * TPN;
    const int4 H = hdr[slot];
    const int* __restrict__ sp = csr_src + H.x;
    const int n = H.y;
    const int i = H.z;
    const float di = __int_as_float(H.w);
    int f0 = c * 8;

    float acc[8];
    {
        union { float4 f; __half2 h[4]; } u;
        u.f = *(const float4*)(hws + (size_t)i * F + f0);  // self loop
#pragma unroll
        for (int j = 0; j < 4; ++j) {
            float2 p = __half22float2(u.h[j]);
            acc[2 * j] = p.x; acc[2 * j + 1] = p.y;
        }
    }

    int k = 0;
    if (n >= 8) {
        int s[8];
#pragma unroll
        for (int j = 0; j < 8; ++j) s[j] = sp[j];
        for (; k + 16 <= n; k += 8) {
            int ns[8];
#pragma unroll
            for (int j = 0; j < 8; ++j) ns[j] = sp[k + 8 + j];
            float4 v[8];
#pragma unroll
            for (int j = 0; j < 8; ++j) v[j] = *(const float4*)(hws + (size_t)s[j] * F + f0);
#pragma unroll
            for (int j = 0; j < 8; ++j) h8_add(acc, v[j]);
#pragma unroll
            for (int j = 0; j < 8; ++j) s[j] = ns[j];
        }
        float4 v[8];
#pragma unroll
        for (int j = 0; j < 8; ++j) v[j] = *(const float4*)(hws + (size_t)s[j] * F + f0);
#pragma unroll
        for (int j = 0; j < 8; ++j) h8_add(acc, v[j]);
        k += 8;
    }
    for (; k + 4 <= n; k += 4) {
        int s0 = sp[k + 0], s1 = sp[k + 1], s2 = sp[k + 2], s3 = sp[k + 3];
        float4 v0 = *(const float4*)(hws + (size_t)s0 * F + f0);
        float4 v1 = *(const float4*)(hws + (size_t)s1 * F + f0);
        float4 v2 = *(const float4*)(hws + (size_t)s2 * F + f0);
        float4 v3 = *(const float4*)(hws + (size_t)s3 * F + f0);
        h8_add(acc, v0); h8_add(acc, v1); h8_add(acc, v2); h8_add(acc, v3);
    }
    for (; k < n; ++k) {
        float4 v = *(const float4*)(hws + (size_t)sp[k] * F + f0);
        h8_add(acc, v);
    }

    float4 r0, r1;
    if (HAS_BIAS) {
        const float4 bb0 = *(const float4*)(b + f0);
        const float4 bb1 = *(const float4*)(b + f0 + 4);
        r0.x = fmaf(acc[0], di, bb0.x); r0.y = fmaf(acc[1], di, bb0.y);
        r0.z = fmaf(acc[2], di, bb0.z); r0.w = fmaf(acc[3], di, bb0.w);
        r1.x = fmaf(acc[4], di, bb1.x); r1.y = fmaf(acc[5], di, bb1.y);
        r1.z = fmaf(acc[6], di, bb1.z); r1.w = fmaf(acc[7], di, bb1.w);
    } else {
        r0.x = acc[0] * di; r0.y = acc[1] * di; r0.z = acc[2] * di; r0.w = acc[3] * di;
        r1.x = acc[4] * di; r1.y = acc[5] * di; r1.z = acc[6] * di; r1.w = acc[7] * di;
    }
    if (OUT_HALF) {
        union { float4 f; __half2 h[4]; } u;
        u.h[0] = __floats2half2_rn(r0.x, r0.y);
        u.h[1] = __floats2half2_rn(r0.z, r0.w);
        u.h[2] = __floats2half2_rn(r1.x, r1.y);
        u.h[3] = __floats2half2_rn(r1.z, r1.w);
        nt_store_raw16((__half*)out_v + (size_t)i * F + f0, u.f);
    } else {
        float* op = (float*)out_v + (size_t)i * F + f0;
        nt_store_raw16(op, r0);
        nt_store_raw16(op + 4, r1);
    }
}

// ---------------- launch ----------------

extern "C" void kernel_launch(void* const* d_in, const int* in_sizes, int n_in,
                              void* d_out, int out_size, void* d_ws, size_t ws_size,
                              hipStream_t stream) {
    const float* x  = (const float*)d_in[0];
    const int*   ei = (const int*)d_in[1];  // (2,E): row0=src, row1=dst
    const float* W1 = (const float*)d_in[2];
    const float* b1 = (const float*)d_in[3];
    const float* W2 = (const float*)d_in[4];
    const float* b2 = (const float*)d_in[5];
    const float* W3 = (const float*)d_in[6];
    const float* b3 = (const float*)d_in[7];
    float* out = (float*)d_out;

    const int N = in_sizes[0] / 12;
    const int E = in_sizes[1] / 2;
    const int NB = cdiv(N, BNODES);  // 196 dst buckets (<=256)

    // workspace layout
    char* ws = (char*)d_ws;
    int*   deg     = (int*)ws;    ws += (size_t)N * sizeof(int);
    int*   row_ptr = (int*)ws;    ws += (size_t)N * sizeof(int);
    int*   bcnt    = (int*)ws;    ws += 256 * sizeof(int);
    int*   dh      = (int*)ws;    ws += 64 * sizeof(int);
    int*   dcur    = (int*)ws;    ws += 64 * sizeof(int);
    float* dinv    = (float*)ws;  ws += (size_t)N * sizeof(float);
    int4*  hdr     = (int4*)ws;   ws += (size_t)N * sizeof(int4);
    __half* W2Th   = (__half*)ws; ws += 128 * 64 * sizeof(__half);
    __half* W3Th   = (__half*)ws; ws += 96 * 128 * sizeof(__half);
    int*   csr_src = (int*)ws;    ws += (size_t)E * sizeof(int);
    float* bufA    = (float*)ws;  ws += (size_t)N * 128 * sizeof(float);  // xs / hw3h
    float* bufB    = (float*)ws;                                          // binned / h1h
    unsigned* binned = (unsigned*)bufB;  // slotted [NB][SLOT]; consumed before h1h

    // ---- CSR build (slotted, bucket_count-free) + weight prep ----
    hipMemsetAsync(bcnt, 0, (256 + 64 + 64) * sizeof(int), stream);  // bcnt+dh+dcur
    prep_w_kernel<<<80, 256, 0, stream>>>(W2, W3, W2Th, W3Th);
    bin_edges_kernel<8192><<<cdiv(E, 8192), BLOCK, 0, stream>>>(ei, E, bcnt, binned, NB);
    csr_fill_kernel<<<NB, 1024, 0, stream>>>(bcnt, binned, deg, dinv, row_ptr,
                                             csr_src, dh, N);

    // ---- degree counting sort -> packed headers (+ prescale folded in) ----
    dperm_kernel<<<cdiv(N, BLOCK), BLOCK, 0, stream>>>(deg, row_ptr, dinv, dh, dcur, hdr,
                                                       x, (__half*)bufA, N);

    // ---- layer 1: fused aggregate@F=16h + 12->64 transform ----
    gather_x_t1_kernel<<<cdiv(N * 2, BLOCK), BLOCK, 0, stream>>>(
        hdr, csr_src, (const __half*)bufA, W1, b1, (__half*)bufB, N);  // bufB = h1h

    // ---- layers 2+3: block-coop gather@F=64 + relu(.@W2+b2)@W3*dinv, ONE kernel ----
    fused_g64_t2t3_kernel<<<cdiv(N / 32, 4), 256, 0, stream>>>(
        (const __half*)bufB, row_ptr, deg, csr_src, dinv, W2Th, b2, W3Th,
        (__half*)bufA, N);  // bufA = hw3h

    // ---- layer 3 aggregate at F=96 (+b3) -> out ----
    gather_h_kernel<96, true, false><<<cdiv(N * 12, BLOCK), BLOCK, 0, stream>>>(
        hdr, csr_src, (const __half*)bufA, b3, out, N);
}